// Round 1
// baseline (408.695 us; speedup 1.0000x reference)
//
#include <hip/hip_runtime.h>
#include <hip/hip_bf16.h>

// Problem constants
#define BB 16
#define TT 512
#define KK 32
#define VV 512
#define DD 64
#define HH 128
#define KV (KK*VV)   // 16384
#define KKK (KK*KK)  // 1024

// ---------------------------------------------------------------------------
// K1: per-token hidden activations  h1 = relu(emb@W1+b1), h2 = relu(emb@E1+e1)
// grid: 512 (token), block: 128 (hidden unit)
__global__ __launch_bounds__(128) void k_hidden(
    const float* __restrict__ emb, const float* __restrict__ W1,
    const float* __restrict__ b1, const float* __restrict__ E1,
    const float* __restrict__ e1, float* __restrict__ h1_tab,
    float* __restrict__ h2_tab) {
  __shared__ float x[DD];
  int u = blockIdx.x, h = threadIdx.x;
  if (h < DD) x[h] = emb[u * DD + h];
  __syncthreads();
  float a1 = b1[h], a2 = e1[h];
#pragma unroll
  for (int d = 0; d < DD; ++d) {
    float xv = x[d];
    a1 += xv * W1[d * HH + h];
    a2 += xv * E1[d * HH + h];
  }
  h1_tab[u * HH + h] = fmaxf(a1, 0.f);
  h2_tab[u * HH + h] = fmaxf(a2, 0.f);
}

// ---------------------------------------------------------------------------
// K0: transpose E2 (128 x 16384) -> E2p (16384 x 128) for coalesced gather
__global__ __launch_bounds__(256) void k_transpose(
    const float* __restrict__ E2, float* __restrict__ E2p) {
  int idx = blockIdx.x * 256 + threadIdx.x;  // over 128*16384
  int h = idx >> 14, col = idx & 16383;
  E2p[col * HH + h] = E2[idx];
}

// ---------------------------------------------------------------------------
// K2: per-token transition table, row-log-softmaxed: (512, 32, 32)
// grid: 512, block: 256
__global__ __launch_bounds__(256) void k_trans(
    const float* __restrict__ h1_tab, const float* __restrict__ W2,
    const float* __restrict__ b2, float* __restrict__ ltrans) {
  __shared__ float h1s[HH];
  __shared__ float lg[KKK];
  __shared__ float lse[KK];
  int u = blockIdx.x, tid = threadIdx.x;
  if (tid < HH) h1s[tid] = h1_tab[u * HH + tid];
  __syncthreads();
  float acc[4];
#pragma unroll
  for (int r = 0; r < 4; ++r) acc[r] = b2[tid + r * 256];
  for (int h = 0; h < HH; ++h) {
    float hv = h1s[h];
#pragma unroll
    for (int r = 0; r < 4; ++r) acc[r] += hv * W2[h * KKK + tid + r * 256];
  }
#pragma unroll
  for (int r = 0; r < 4; ++r) lg[tid + r * 256] = acc[r];
  __syncthreads();
  if (tid < KK) {
    float m = -1e30f;
    for (int j = 0; j < KK; ++j) m = fmaxf(m, lg[tid * KK + j]);
    float s = 0.f;
    for (int j = 0; j < KK; ++j) s += __expf(lg[tid * KK + j] - m);
    lse[tid] = m + __logf(s);
  }
  __syncthreads();
#pragma unroll
  for (int r = 0; r < 4; ++r) {
    int c = tid + r * 256;
    ltrans[u * KKK + c] = lg[c] - lse[c >> 5];
  }
}

// ---------------------------------------------------------------------------
// K3: emission GEMM (512 x 16384) = h2_tab(512x128) @ E2(128x16384) + e2,
// fused per-tile (max, sumexp) partials. Tile 64x64, block 256.
// grid: (256 col-tiles, 8 row-tiles)
__global__ __launch_bounds__(256) void k_emit_gemm(
    const float* __restrict__ h2_tab, const float* __restrict__ E2,
    const float* __restrict__ e2, float* __restrict__ part_m,
    float* __restrict__ part_s) {
  __shared__ float As[64 * 65];
  __shared__ float Bs[64 * 64];
  int bn = blockIdx.x, bu = blockIdx.y;
  int tid = threadIdx.x;
  int tx = tid & 15, ty = tid >> 4;
  float accv[4][4] = {{0.f}};
  for (int kt = 0; kt < 2; ++kt) {
    __syncthreads();
#pragma unroll
    for (int r = 0; r < 16; ++r) {
      int idx = r * 256 + tid;
      int row = idx >> 6, kk = idx & 63;
      As[row * 65 + kk] = h2_tab[(bu * 64 + row) * HH + kt * 64 + kk];
      Bs[idx] = E2[(kt * 64 + row) * KV + bn * 64 + kk];
    }
    __syncthreads();
    for (int kk = 0; kk < 64; ++kk) {
      float a[4], bv[4];
#pragma unroll
      for (int i = 0; i < 4; ++i) a[i] = As[(ty * 4 + i) * 65 + kk];
#pragma unroll
      for (int jj = 0; jj < 4; ++jj) bv[jj] = Bs[kk * 64 + tx * 4 + jj];
#pragma unroll
      for (int i = 0; i < 4; ++i)
#pragma unroll
        for (int jj = 0; jj < 4; ++jj) accv[i][jj] += a[i] * bv[jj];
    }
  }
  float e2v[4];
#pragma unroll
  for (int jj = 0; jj < 4; ++jj) e2v[jj] = e2[bn * 64 + tx * 4 + jj];
#pragma unroll
  for (int i = 0; i < 4; ++i)
#pragma unroll
    for (int jj = 0; jj < 4; ++jj) accv[i][jj] += e2v[jj];

  int kcol = bn >> 3, tseg = bn & 7;
#pragma unroll
  for (int i = 0; i < 4; ++i) {
    float m = fmaxf(fmaxf(accv[i][0], accv[i][1]), fmaxf(accv[i][2], accv[i][3]));
#pragma unroll
    for (int d = 1; d < 16; d <<= 1) m = fmaxf(m, __shfl_xor(m, d));
    float s = 0.f;
#pragma unroll
    for (int jj = 0; jj < 4; ++jj) s += __expf(accv[i][jj] - m);
#pragma unroll
    for (int d = 1; d < 16; d <<= 1) s += __shfl_xor(s, d);
    if (tx == 0) {
      int u = bu * 64 + ty * 4 + i;
      int pi = (u * KK + kcol) * 8 + tseg;
      part_m[pi] = m;
      part_s[pi] = s;
    }
  }
}

// ---------------------------------------------------------------------------
// K4: combine 8 tile partials -> lse_tab (512*32)
__global__ __launch_bounds__(256) void k_lsecomb(
    const float* __restrict__ pm, const float* __restrict__ ps,
    float* __restrict__ lse_tab) {
  int i = blockIdx.x * 256 + threadIdx.x;  // 16384
  float m = -1e30f, s = 0.f;
#pragma unroll
  for (int t = 0; t < 8; ++t) {
    float mm = pm[i * 8 + t], ss = ps[i * 8 + t];
    float nm = fmaxf(m, mm);
    s = s * __expf(m - nm) + ss * __expf(mm - nm);
    m = nm;
  }
  lse_tab[i] = m + __logf(s);
}

// ---------------------------------------------------------------------------
// K5: emission scores es[b,t,k] = dot(h2[u], E2p[k*512+y]) + e2 - lse
// grid: B*T blocks of 64 (lane = (k, half-of-H))
__global__ __launch_bounds__(64) void k_es(
    const int* __restrict__ seq, const float* __restrict__ h2_tab,
    const float* __restrict__ E2p, const float* __restrict__ e2,
    const float* __restrict__ lse_tab, float* __restrict__ es) {
  int bt = blockIdx.x;  // 0..8191
  int b = bt >> 9, t = bt & 511;
  int l = threadIdx.x;
  int k = l >> 1, half = l & 1;
  int y = seq[b * TT + t];
  int u = (t == 0) ? 0 : seq[b * TT + t - 1];
  const float4* hv = (const float4*)(h2_tab + u * HH + half * 64);
  const float4* ev = (const float4*)(E2p + (k * VV + y) * HH + half * 64);
  float acc = 0.f;
#pragma unroll
  for (int r = 0; r < 16; ++r) {
    float4 a = hv[r], bq = ev[r];
    acc += a.x * bq.x + a.y * bq.y + a.z * bq.z + a.w * bq.w;
  }
  acc += __shfl_xor(acc, 1);
  if (half == 0) es[bt * KK + k] = acc + e2[k * VV + y] - lse_tab[u * KK + k];
}

// ---------------------------------------------------------------------------
// K6: forward recursion. 1 block (1 wave) per batch element.
// lane l -> (j = l&31 output state, half = l>>5 covers 16 of the 32 i's)
__global__ __launch_bounds__(64) void k_forward(
    const int* __restrict__ seq, const int* __restrict__ lengths,
    const float* __restrict__ ltrans, const float* __restrict__ es,
    const float* __restrict__ init_logits, float* __restrict__ out) {
  int b = blockIdx.x;
  int l = threadIdx.x;
  int j = l & 31, half = l >> 5;
  __shared__ float alpha_s[KK];

  // init log-softmax over init_logits (32)
  float il = init_logits[j];
  float m0 = il;
#pragma unroll
  for (int d = 1; d < 32; d <<= 1) m0 = fmaxf(m0, __shfl_xor(m0, d));
  float s0 = __expf(il - m0);
#pragma unroll
  for (int d = 1; d < 32; d <<= 1) s0 += __shfl_xor(s0, d);
  float lse0 = m0 + __logf(s0);

  int len = lengths[b];
  if (len > TT) len = TT;
  if (len < 1) len = 1;
  const int* sb = seq + b * TT;

  if (half == 0) alpha_s[j] = il - lse0 + es[(b * TT) * KK + j];
  __syncthreads();

  float ltc[16], esc = 0.f;
  if (len > 1) {
    int u = sb[0];
    const float* p = ltrans + u * KKK + (half * 16) * KK + j;
#pragma unroll
    for (int r = 0; r < 16; ++r) ltc[r] = p[r * KK];
    esc = es[(b * TT + 1) * KK + j];
  }

  for (int t = 1; t < len; ++t) {
    // prefetch next step while computing current
    float ltn[16];
    float esn = 0.f;
#pragma unroll
    for (int r = 0; r < 16; ++r) ltn[r] = 0.f;
    if (t + 1 < len) {
      int u = sb[t];
      const float* p = ltrans + u * KKK + (half * 16) * KK + j;
#pragma unroll
      for (int r = 0; r < 16; ++r) ltn[r] = p[r * KK];
      esn = es[(b * TT + t + 1) * KK + j];
    }

    float v[16];
    float m = -1e30f;
#pragma unroll
    for (int r = 0; r < 16; ++r) {
      v[r] = alpha_s[half * 16 + r] + ltc[r];
      m = fmaxf(m, v[r]);
    }
    float s = 0.f;
#pragma unroll
    for (int r = 0; r < 16; ++r) s += __expf(v[r] - m);
    // combine halves (i in [0,16) with i in [16,32))
    float mo = __shfl_xor(m, 32);
    float so = __shfl_xor(s, 32);
    float mm = fmaxf(m, mo);
    float ss = s * __expf(m - mm) + so * __expf(mo - mm);
    float na = mm + __logf(ss) + esc;
    __syncthreads();
    if (half == 0) alpha_s[j] = na;
    __syncthreads();
#pragma unroll
    for (int r = 0; r < 16; ++r) ltc[r] = ltn[r];
    esc = esn;
  }

  // final: out[b] = -logsumexp_j alpha[j]
  float av = alpha_s[j];
  float mf = av;
#pragma unroll
  for (int d = 1; d < 32; d <<= 1) mf = fmaxf(mf, __shfl_xor(mf, d));
  float sf = __expf(av - mf);
#pragma unroll
  for (int d = 1; d < 32; d <<= 1) sf += __shfl_xor(sf, d);
  if (l == 0) out[b] = -(mf + __logf(sf));
}

// ---------------------------------------------------------------------------
extern "C" void kernel_launch(void* const* d_in, const int* in_sizes, int n_in,
                              void* d_out, int out_size, void* d_ws,
                              size_t ws_size, hipStream_t stream) {
  const int* seq = (const int*)d_in[0];
  const int* lengths = (const int*)d_in[1];
  const float* emb = (const float*)d_in[2];
  const float* W1 = (const float*)d_in[3];
  const float* b1 = (const float*)d_in[4];
  const float* W2 = (const float*)d_in[5];
  const float* b2 = (const float*)d_in[6];
  const float* E1 = (const float*)d_in[7];
  const float* e1 = (const float*)d_in[8];
  const float* E2 = (const float*)d_in[9];
  const float* e2 = (const float*)d_in[10];
  const float* init_logits = (const float*)d_in[11];
  float* out = (float*)d_out;

  float* ws = (float*)d_ws;
  float* h1_tab = ws;                       // 512*128
  float* h2_tab = h1_tab + 512 * 128;       // 512*128
  float* ltrans = h2_tab + 512 * 128;       // 512*1024
  float* E2p = ltrans + 512 * 1024;         // 16384*128
  float* part_m = E2p + 16384 * 128;        // 512*32*8
  float* part_s = part_m + 512 * 32 * 8;    // 512*32*8
  float* lse_tab = part_s + 512 * 32 * 8;   // 512*32
  float* es = lse_tab + 512 * 32;           // 16*512*32

  k_hidden<<<512, 128, 0, stream>>>(emb, W1, b1, E1, e1, h1_tab, h2_tab);
  k_transpose<<<8192, 256, 0, stream>>>(E2, E2p);
  k_trans<<<512, 256, 0, stream>>>(h1_tab, W2, b2, ltrans);
  k_emit_gemm<<<dim3(256, 8), 256, 0, stream>>>(h2_tab, E2, e2, part_m, part_s);
  k_lsecomb<<<64, 256, 0, stream>>>(part_m, part_s, lse_tab);
  k_es<<<8192, 64, 0, stream>>>(seq, h2_tab, E2p, e2, lse_tab, es);
  k_forward<<<16, 64, 0, stream>>>(seq, lengths, ltrans, es, init_logits, out);
}

// Round 2
// 329.225 us; speedup vs baseline: 1.2414x; 1.2414x over previous
//
#include <hip/hip_runtime.h>
#include <hip/hip_bf16.h>

// Problem constants
#define BB 16
#define TT 512
#define KK 32
#define VV 512
#define DD 64
#define HH 128
#define KV (KK*VV)   // 16384
#define KKK (KK*KK)  // 1024

#define INV_LN2 1.4426950408889634f
#define LN2 0.6931471805599453f

__device__ __forceinline__ float fexp2(float x) { return __builtin_amdgcn_exp2f(x); }
__device__ __forceinline__ float flog2(float x) { return __builtin_amdgcn_logf(x); }

// ---------------------------------------------------------------------------
// K1: per-token hidden activations  h1 = relu(emb@W1+b1), h2 = relu(emb@E1+e1)
__global__ __launch_bounds__(128) void k_hidden(
    const float* __restrict__ emb, const float* __restrict__ W1,
    const float* __restrict__ b1, const float* __restrict__ E1,
    const float* __restrict__ e1, float* __restrict__ h1_tab,
    float* __restrict__ h2_tab) {
  __shared__ float x[DD];
  int u = blockIdx.x, h = threadIdx.x;
  if (h < DD) x[h] = emb[u * DD + h];
  __syncthreads();
  float a1 = b1[h], a2 = e1[h];
#pragma unroll
  for (int d = 0; d < DD; ++d) {
    float xv = x[d];
    a1 += xv * W1[d * HH + h];
    a2 += xv * E1[d * HH + h];
  }
  h1_tab[u * HH + h] = fmaxf(a1, 0.f);
  h2_tab[u * HH + h] = fmaxf(a2, 0.f);
}

// ---------------------------------------------------------------------------
// K0: transpose E2 (128 x 16384) -> E2p (16384 x 128) for coalesced gather
__global__ __launch_bounds__(256) void k_transpose(
    const float* __restrict__ E2, float* __restrict__ E2p) {
  int idx = blockIdx.x * 256 + threadIdx.x;  // over 128*16384
  int h = idx >> 14, col = idx & 16383;
  E2p[col * HH + h] = E2[idx];
}

// ---------------------------------------------------------------------------
// K2: per-token transition table, row-log-softmaxed, stored TRANSPOSED and
// scaled to log2 domain: ltrans_T[u*1024 + j*32 + i] = (lg[i][j]-lse[i])/ln2
__global__ __launch_bounds__(256) void k_trans(
    const float* __restrict__ h1_tab, const float* __restrict__ W2,
    const float* __restrict__ b2, float* __restrict__ ltrans) {
  __shared__ float h1s[HH];
  __shared__ float lg[KK * 33];  // padded [i*33+j], conflict-free transpose read
  __shared__ float lse[KK];
  int u = blockIdx.x, tid = threadIdx.x;
  if (tid < HH) h1s[tid] = h1_tab[u * HH + tid];
  __syncthreads();
  float acc[4];
#pragma unroll
  for (int r = 0; r < 4; ++r) acc[r] = b2[tid + r * 256];
  for (int h = 0; h < HH; ++h) {
    float hv = h1s[h];
#pragma unroll
    for (int r = 0; r < 4; ++r) acc[r] += hv * W2[h * KKK + tid + r * 256];
  }
#pragma unroll
  for (int r = 0; r < 4; ++r) {
    int c = tid + r * 256;                 // c = i*32 + j (row-major logits)
    lg[(c >> 5) * 33 + (c & 31)] = acc[r] * INV_LN2;  // log2 domain
  }
  __syncthreads();
  if (tid < KK) {  // row i = tid: log2-softmax denominator
    float m = -1e30f;
    for (int jj = 0; jj < KK; ++jj) m = fmaxf(m, lg[tid * 33 + jj]);
    float s = 0.f;
    for (int jj = 0; jj < KK; ++jj) s += fexp2(lg[tid * 33 + jj] - m);
    lse[tid] = m + flog2(s);
  }
  __syncthreads();
#pragma unroll
  for (int r = 0; r < 4; ++r) {
    int c = tid + r * 256;                 // c = j*32 + i (transposed layout)
    int jj = c >> 5, ii = c & 31;
    ltrans[u * KKK + jj * KK + ii] = lg[ii * 33 + jj] - lse[ii];
  }
}

// ---------------------------------------------------------------------------
// K3: emission GEMM (512 x 16384) = h2_tab(512x128) @ E2(128x16384) + e2,
// fused per-tile (max, sumexp) partials (e-domain). Tile 64x64, block 256.
__global__ __launch_bounds__(256) void k_emit_gemm(
    const float* __restrict__ h2_tab, const float* __restrict__ E2,
    const float* __restrict__ e2, float* __restrict__ part_m,
    float* __restrict__ part_s) {
  __shared__ float As[64 * 65];
  __shared__ float Bs[64 * 64];
  int bn = blockIdx.x, bu = blockIdx.y;
  int tid = threadIdx.x;
  int tx = tid & 15, ty = tid >> 4;
  float accv[4][4] = {{0.f}};
  for (int kt = 0; kt < 2; ++kt) {
    __syncthreads();
#pragma unroll
    for (int r = 0; r < 16; ++r) {
      int idx = r * 256 + tid;
      int row = idx >> 6, kk = idx & 63;
      As[row * 65 + kk] = h2_tab[(bu * 64 + row) * HH + kt * 64 + kk];
      Bs[idx] = E2[(kt * 64 + row) * KV + bn * 64 + kk];
    }
    __syncthreads();
    for (int kk = 0; kk < 64; ++kk) {
      float a[4], bv[4];
#pragma unroll
      for (int i = 0; i < 4; ++i) a[i] = As[(ty * 4 + i) * 65 + kk];
#pragma unroll
      for (int jj = 0; jj < 4; ++jj) bv[jj] = Bs[kk * 64 + tx * 4 + jj];
#pragma unroll
      for (int i = 0; i < 4; ++i)
#pragma unroll
        for (int jj = 0; jj < 4; ++jj) accv[i][jj] += a[i] * bv[jj];
    }
  }
  float e2v[4];
#pragma unroll
  for (int jj = 0; jj < 4; ++jj) e2v[jj] = e2[bn * 64 + tx * 4 + jj];
#pragma unroll
  for (int i = 0; i < 4; ++i)
#pragma unroll
    for (int jj = 0; jj < 4; ++jj) accv[i][jj] += e2v[jj];

  int kcol = bn >> 3, tseg = bn & 7;
#pragma unroll
  for (int i = 0; i < 4; ++i) {
    float m = fmaxf(fmaxf(accv[i][0], accv[i][1]), fmaxf(accv[i][2], accv[i][3]));
#pragma unroll
    for (int d = 1; d < 16; d <<= 1) m = fmaxf(m, __shfl_xor(m, d));
    float s = 0.f;
#pragma unroll
    for (int jj = 0; jj < 4; ++jj) s += __expf(accv[i][jj] - m);
#pragma unroll
    for (int d = 1; d < 16; d <<= 1) s += __shfl_xor(s, d);
    if (tx == 0) {
      int u = bu * 64 + ty * 4 + i;
      int pi = (u * KK + kcol) * 8 + tseg;
      part_m[pi] = m;
      part_s[pi] = s;
    }
  }
}

// ---------------------------------------------------------------------------
// K4: combine 8 tile partials -> lse_tab (512*32), e-domain
__global__ __launch_bounds__(256) void k_lsecomb(
    const float* __restrict__ pm, const float* __restrict__ ps,
    float* __restrict__ lse_tab) {
  int i = blockIdx.x * 256 + threadIdx.x;  // 16384
  float m = -1e30f, s = 0.f;
#pragma unroll
  for (int t = 0; t < 8; ++t) {
    float mm = pm[i * 8 + t], ss = ps[i * 8 + t];
    float nm = fmaxf(m, mm);
    s = s * __expf(m - nm) + ss * __expf(mm - nm);
    m = nm;
  }
  lse_tab[i] = m + __logf(s);
}

// ---------------------------------------------------------------------------
// K5: emission scores (log2 domain):
// es[b,t,k] = (dot(h2[u], E2p[k*512+y]) + e2 - lse) / ln2
__global__ __launch_bounds__(64) void k_es(
    const int* __restrict__ seq, const float* __restrict__ h2_tab,
    const float* __restrict__ E2p, const float* __restrict__ e2,
    const float* __restrict__ lse_tab, float* __restrict__ es) {
  int bt = blockIdx.x;  // 0..8191
  int b = bt >> 9, t = bt & 511;
  int l = threadIdx.x;
  int k = l >> 1, half = l & 1;
  int y = seq[b * TT + t];
  int u = (t == 0) ? 0 : seq[b * TT + t - 1];
  const float4* hv = (const float4*)(h2_tab + u * HH + half * 64);
  const float4* ev = (const float4*)(E2p + (k * VV + y) * HH + half * 64);
  float acc = 0.f;
#pragma unroll
  for (int r = 0; r < 16; ++r) {
    float4 a = hv[r], bq = ev[r];
    acc += a.x * bq.x + a.y * bq.y + a.z * bq.z + a.w * bq.w;
  }
  acc += __shfl_xor(acc, 1);
  if (half == 0)
    es[bt * KK + k] = (acc + e2[k * VV + y] - lse_tab[u * KK + k]) * INV_LN2;
}

// ---------------------------------------------------------------------------
// K6: forward recursion. 1 block (1 wave) per batch element.
// lane l -> (j = l&31 output state, half = l>>5 covers 16 of 32 i's)
// alpha kept in registers (lane j holds alpha[j], replicated across halves),
// exchanged via bpermute shuffles. Depth-2 prefetch, 3 rotating reg buffers.
// Everything in log2 domain.
__global__ __launch_bounds__(64) void k_forward(
    const int* __restrict__ seq, const int* __restrict__ lengths,
    const float* __restrict__ ltrans, const float* __restrict__ es,
    const float* __restrict__ init_logits, float* __restrict__ out) {
  int b = blockIdx.x;
  int l = threadIdx.x;
  int j = l & 31, half = l >> 5;
  __shared__ int sb_s[TT];
#pragma unroll
  for (int r = 0; r < 8; ++r) sb_s[r * 64 + l] = seq[b * TT + r * 64 + l];
  __syncthreads();

  const float* esb = es + b * TT * KK;

  // init log2-softmax over init_logits (32)
  float il = init_logits[j] * INV_LN2;
  float m0 = il;
#pragma unroll
  for (int d = 1; d < 32; d <<= 1) m0 = fmaxf(m0, __shfl_xor(m0, d));
  float s0 = fexp2(il - m0);
#pragma unroll
  for (int d = 1; d < 32; d <<= 1) s0 += __shfl_xor(s0, d);
  float lse0 = m0 + flog2(s0);

  int len = lengths[b];
  if (len > TT) len = TT;
  if (len < 1) len = 1;

  float a = il - lse0 + esb[j];  // alpha0 (log2 domain)

  float lt0[16], lt1[16], lt2[16];
  float es0v = 0.f, es1v = 0.f, es2v = 0.f;

#define LOADSTEP(LT, ES, tt)                                                \
  {                                                                         \
    int u = sb_s[(tt)-1];                                                   \
    const float4* p4 = (const float4*)(ltrans + u * KKK + j * KK + half * 16); \
    float4 q0 = p4[0], q1 = p4[1], q2 = p4[2], q3 = p4[3];                  \
    LT[0] = q0.x; LT[1] = q0.y; LT[2] = q0.z; LT[3] = q0.w;                 \
    LT[4] = q1.x; LT[5] = q1.y; LT[6] = q1.z; LT[7] = q1.w;                 \
    LT[8] = q2.x; LT[9] = q2.y; LT[10] = q2.z; LT[11] = q2.w;               \
    LT[12] = q3.x; LT[13] = q3.y; LT[14] = q3.z; LT[15] = q3.w;             \
    ES = esb[(tt)*KK + j];                                                  \
  }

#define COMPUTE(LT, ES)                                                     \
  {                                                                         \
    float vv[16];                                                           \
    _Pragma("unroll") for (int r = 0; r < 16; ++r)                          \
        vv[r] = __shfl(a, half * 16 + r, 64) + LT[r];                       \
    float m8[8];                                                            \
    _Pragma("unroll") for (int r = 0; r < 8; ++r)                           \
        m8[r] = fmaxf(vv[2 * r], vv[2 * r + 1]);                            \
    float m4[4];                                                            \
    _Pragma("unroll") for (int r = 0; r < 4; ++r)                           \
        m4[r] = fmaxf(m8[2 * r], m8[2 * r + 1]);                            \
    float m = fmaxf(fmaxf(m4[0], m4[1]), fmaxf(m4[2], m4[3]));              \
    float s8[8];                                                            \
    _Pragma("unroll") for (int r = 0; r < 8; ++r)                           \
        s8[r] = fexp2(vv[2 * r] - m) + fexp2(vv[2 * r + 1] - m);            \
    float s4[4];                                                            \
    _Pragma("unroll") for (int r = 0; r < 4; ++r) s4[r] = s8[2 * r] + s8[2 * r + 1]; \
    float s = (s4[0] + s4[1]) + (s4[2] + s4[3]);                            \
    float mo = __shfl_xor(m, 32);                                           \
    float so = __shfl_xor(s, 32);                                           \
    float mm = fmaxf(m, mo);                                                \
    float ss = s * fexp2(m - mm) + so * fexp2(mo - mm);                     \
    a = mm + flog2(ss) + ES;                                                \
  }

  if (len > 1) LOADSTEP(lt1, es1v, 1);
  if (len > 2) LOADSTEP(lt2, es2v, 2);

  int t = 1;
  while (t < len) {
    if (t + 2 < len) LOADSTEP(lt0, es0v, t + 2);
    COMPUTE(lt1, es1v);
    ++t;
    if (t >= len) break;
    if (t + 2 < len) LOADSTEP(lt1, es1v, t + 2);
    COMPUTE(lt2, es2v);
    ++t;
    if (t >= len) break;
    if (t + 2 < len) LOADSTEP(lt2, es2v, t + 2);
    COMPUTE(lt0, es0v);
    ++t;
  }

  // final: out[b] = -ln2 * logsumexp2_j alpha[j]
  float mf = a;
#pragma unroll
  for (int d = 1; d < 32; d <<= 1) mf = fmaxf(mf, __shfl_xor(mf, d));
  float sf = fexp2(a - mf);
#pragma unroll
  for (int d = 1; d < 32; d <<= 1) sf += __shfl_xor(sf, d);
  if (l == 0) out[b] = -LN2 * (mf + flog2(sf));
}

// ---------------------------------------------------------------------------
extern "C" void kernel_launch(void* const* d_in, const int* in_sizes, int n_in,
                              void* d_out, int out_size, void* d_ws,
                              size_t ws_size, hipStream_t stream) {
  const int* seq = (const int*)d_in[0];
  const int* lengths = (const int*)d_in[1];
  const float* emb = (const float*)d_in[2];
  const float* W1 = (const float*)d_in[3];
  const float* b1 = (const float*)d_in[4];
  const float* W2 = (const float*)d_in[5];
  const float* b2 = (const float*)d_in[6];
  const float* E1 = (const float*)d_in[7];
  const float* e1 = (const float*)d_in[8];
  const float* E2 = (const float*)d_in[9];
  const float* e2 = (const float*)d_in[10];
  const float* init_logits = (const float*)d_in[11];
  float* out = (float*)d_out;

  float* ws = (float*)d_ws;
  float* h1_tab = ws;                       // 512*128
  float* h2_tab = h1_tab + 512 * 128;       // 512*128
  float* ltrans = h2_tab + 512 * 128;       // 512*1024 (transposed, log2)
  float* E2p = ltrans + 512 * 1024;         // 16384*128
  float* part_m = E2p + 16384 * 128;        // 512*32*8
  float* part_s = part_m + 512 * 32 * 8;    // 512*32*8
  float* lse_tab = part_s + 512 * 32 * 8;   // 512*32
  float* es = lse_tab + 512 * 32;           // 16*512*32 (log2 domain)

  k_hidden<<<512, 128, 0, stream>>>(emb, W1, b1, E1, e1, h1_tab, h2_tab);
  k_transpose<<<8192, 256, 0, stream>>>(E2, E2p);
  k_trans<<<512, 256, 0, stream>>>(h1_tab, W2, b2, ltrans);
  k_emit_gemm<<<dim3(256, 8), 256, 0, stream>>>(h2_tab, E2, e2, part_m, part_s);
  k_lsecomb<<<64, 256, 0, stream>>>(part_m, part_s, lse_tab);
  k_es<<<8192, 64, 0, stream>>>(seq, h2_tab, E2p, e2, lse_tab, es);
  k_forward<<<16, 64, 0, stream>>>(seq, lengths, ltrans, es, init_logits, out);
}

// Round 3
// 126.192 us; speedup vs baseline: 3.2387x; 2.6089x over previous
//
#include <hip/hip_runtime.h>
#include <hip/hip_bf16.h>

// Problem constants
#define BB 16
#define TT 512
#define KK 32
#define VV 512
#define DD 64
#define HH 128
#define KV (KK*VV)   // 16384
#define KKK (KK*KK)  // 1024

#define INV_LN2 1.4426950408889634f
#define LN2 0.6931471805599453f

typedef unsigned short u16;
typedef __attribute__((ext_vector_type(8))) short short8;
typedef __attribute__((ext_vector_type(8))) unsigned short ushort8;
typedef __attribute__((ext_vector_type(16))) float f32x16;

__device__ __forceinline__ float fexp2(float x) { return __builtin_amdgcn_exp2f(x); }
__device__ __forceinline__ float flog2(float x) { return __builtin_amdgcn_logf(x); }

// float -> bf16 bits, round-nearest-even (finite inputs only)
__device__ __forceinline__ u16 f2bf(float f) {
  unsigned u = __builtin_bit_cast(unsigned, f);
  u += 0x7FFFu + ((u >> 16) & 1u);
  return (u16)(u >> 16);
}

// ---------------------------------------------------------------------------
// K1: per-token hidden activations  h1 = relu(emb@W1+b1), h2 = relu(emb@E1+e1)
__global__ __launch_bounds__(128) void k_hidden(
    const float* __restrict__ emb, const float* __restrict__ W1,
    const float* __restrict__ b1, const float* __restrict__ E1,
    const float* __restrict__ e1, float* __restrict__ h1_tab,
    float* __restrict__ h2_tab) {
  __shared__ float x[DD];
  int u = blockIdx.x, h = threadIdx.x;
  if (h < DD) x[h] = emb[u * DD + h];
  __syncthreads();
  float a1 = b1[h], a2 = e1[h];
#pragma unroll
  for (int d = 0; d < DD; ++d) {
    float xv = x[d];
    a1 += xv * W1[d * HH + h];
    a2 += xv * E1[d * HH + h];
  }
  h1_tab[u * HH + h] = fmaxf(a1, 0.f);
  h2_tab[u * HH + h] = fmaxf(a2, 0.f);
}

// ---------------------------------------------------------------------------
// K0: transpose E2 (128 x 16384) -> E2p (16384 x 128) for coalesced gather
__global__ __launch_bounds__(256) void k_transpose(
    const float* __restrict__ E2, float* __restrict__ E2p) {
  int idx = blockIdx.x * 256 + threadIdx.x;  // over 128*16384
  int h = idx >> 14, col = idx & 16383;
  E2p[col * HH + h] = E2[idx];
}

// ---------------------------------------------------------------------------
// K2: per-token transition table, row-log-softmaxed, stored TRANSPOSED and
// scaled to log2 domain: ltrans_T[u*1024 + j*32 + i] = (lg[i][j]-lse[i])/ln2
__global__ __launch_bounds__(256) void k_trans(
    const float* __restrict__ h1_tab, const float* __restrict__ W2,
    const float* __restrict__ b2, float* __restrict__ ltrans) {
  __shared__ float h1s[HH];
  __shared__ float lg[KK * 33];
  __shared__ float lse[KK];
  int u = blockIdx.x, tid = threadIdx.x;
  if (tid < HH) h1s[tid] = h1_tab[u * HH + tid];
  __syncthreads();
  float acc[4];
#pragma unroll
  for (int r = 0; r < 4; ++r) acc[r] = b2[tid + r * 256];
  for (int h = 0; h < HH; ++h) {
    float hv = h1s[h];
#pragma unroll
    for (int r = 0; r < 4; ++r) acc[r] += hv * W2[h * KKK + tid + r * 256];
  }
#pragma unroll
  for (int r = 0; r < 4; ++r) {
    int c = tid + r * 256;                 // c = i*32 + j
    lg[(c >> 5) * 33 + (c & 31)] = acc[r] * INV_LN2;
  }
  __syncthreads();
  if (tid < KK) {
    float m = -1e30f;
    for (int jj = 0; jj < KK; ++jj) m = fmaxf(m, lg[tid * 33 + jj]);
    float s = 0.f;
    for (int jj = 0; jj < KK; ++jj) s += fexp2(lg[tid * 33 + jj] - m);
    lse[tid] = m + flog2(s);
  }
  __syncthreads();
#pragma unroll
  for (int r = 0; r < 4; ++r) {
    int c = tid + r * 256;                 // c = j*32 + i (transposed layout)
    int jj = c >> 5, ii = c & 31;
    ltrans[u * KKK + jj * KK + ii] = lg[ii * 33 + jj] - lse[ii];
  }
}

// ---------------------------------------------------------------------------
// K3: emission GEMM (512 x 16384) with fused per-tile (max,sumexp) partials
__global__ __launch_bounds__(256) void k_emit_gemm(
    const float* __restrict__ h2_tab, const float* __restrict__ E2,
    const float* __restrict__ e2, float* __restrict__ part_m,
    float* __restrict__ part_s) {
  __shared__ float As[64 * 65];
  __shared__ float Bs[64 * 64];
  int bn = blockIdx.x, bu = blockIdx.y;
  int tid = threadIdx.x;
  int tx = tid & 15, ty = tid >> 4;
  float accv[4][4] = {{0.f}};
  for (int kt = 0; kt < 2; ++kt) {
    __syncthreads();
#pragma unroll
    for (int r = 0; r < 16; ++r) {
      int idx = r * 256 + tid;
      int row = idx >> 6, kk = idx & 63;
      As[row * 65 + kk] = h2_tab[(bu * 64 + row) * HH + kt * 64 + kk];
      Bs[idx] = E2[(kt * 64 + row) * KV + bn * 64 + kk];
    }
    __syncthreads();
    for (int kk = 0; kk < 64; ++kk) {
      float a[4], bv[4];
#pragma unroll
      for (int i = 0; i < 4; ++i) a[i] = As[(ty * 4 + i) * 65 + kk];
#pragma unroll
      for (int jj = 0; jj < 4; ++jj) bv[jj] = Bs[kk * 64 + tx * 4 + jj];
#pragma unroll
      for (int i = 0; i < 4; ++i)
#pragma unroll
        for (int jj = 0; jj < 4; ++jj) accv[i][jj] += a[i] * bv[jj];
    }
  }
  float e2v[4];
#pragma unroll
  for (int jj = 0; jj < 4; ++jj) e2v[jj] = e2[bn * 64 + tx * 4 + jj];
#pragma unroll
  for (int i = 0; i < 4; ++i)
#pragma unroll
    for (int jj = 0; jj < 4; ++jj) accv[i][jj] += e2v[jj];

  int kcol = bn >> 3, tseg = bn & 7;
#pragma unroll
  for (int i = 0; i < 4; ++i) {
    float m = fmaxf(fmaxf(accv[i][0], accv[i][1]), fmaxf(accv[i][2], accv[i][3]));
#pragma unroll
    for (int d = 1; d < 16; d <<= 1) m = fmaxf(m, __shfl_xor(m, d));
    float s = 0.f;
#pragma unroll
    for (int jj = 0; jj < 4; ++jj) s += __expf(accv[i][jj] - m);
#pragma unroll
    for (int d = 1; d < 16; d <<= 1) s += __shfl_xor(s, d);
    if (tx == 0) {
      int u = bu * 64 + ty * 4 + i;
      int pi = (u * KK + kcol) * 8 + tseg;
      part_m[pi] = m;
      part_s[pi] = s;
    }
  }
}

// ---------------------------------------------------------------------------
// K4: combine 8 tile partials -> lse_tab (512*32), e-domain
__global__ __launch_bounds__(256) void k_lsecomb(
    const float* __restrict__ pm, const float* __restrict__ ps,
    float* __restrict__ lse_tab) {
  int i = blockIdx.x * 256 + threadIdx.x;  // 16384
  float m = -1e30f, s = 0.f;
#pragma unroll
  for (int t = 0; t < 8; ++t) {
    float mm = pm[i * 8 + t], ss = ps[i * 8 + t];
    float nm = fmaxf(m, mm);
    s = s * __expf(m - nm) + ss * __expf(mm - nm);
    m = nm;
  }
  lse_tab[i] = m + __logf(s);
}

// ---------------------------------------------------------------------------
// K5: emission scores (log2 domain)
__global__ __launch_bounds__(64) void k_es(
    const int* __restrict__ seq, const float* __restrict__ h2_tab,
    const float* __restrict__ E2p, const float* __restrict__ e2,
    const float* __restrict__ lse_tab, float* __restrict__ es) {
  int bt = blockIdx.x;  // 0..8191
  int b = bt >> 9, t = bt & 511;
  int l = threadIdx.x;
  int k = l >> 1, half = l & 1;
  int y = seq[b * TT + t];
  int u = (t == 0) ? 0 : seq[b * TT + t - 1];
  const float4* hv = (const float4*)(h2_tab + u * HH + half * 64);
  const float4* ev = (const float4*)(E2p + (k * VV + y) * HH + half * 64);
  float acc = 0.f;
#pragma unroll
  for (int r = 0; r < 16; ++r) {
    float4 a = hv[r], bq = ev[r];
    acc += a.x * bq.x + a.y * bq.y + a.z * bq.z + a.w * bq.w;
  }
  acc += __shfl_xor(acc, 1);
  if (half == 0)
    es[bt * KK + k] = (acc + e2[k * VV + y] - lse_tab[u * KK + k]) * INV_LN2;
}

// ---------------------------------------------------------------------------
// K6: build normalized step matrices M_t^T in bf16 (row-major 32x32 per (b,t))
//   M_t[i][j] = Tr[u_t][i][j]*E_t[j]  =>  M^T[j][i], scale = log2 max.
//   slot t=0 and t>=len are Identity (scale 0).
__global__ __launch_bounds__(64) void k_mat(
    const int* __restrict__ seq, const int* __restrict__ lengths,
    const float* __restrict__ ltrans, const float* __restrict__ es,
    u16* __restrict__ Mb, float* __restrict__ msc) {
  int bt = blockIdx.x;
  int b = bt >> 9, t = bt & 511;
  int l = threadIdx.x;
  int j = l & 31, ih = l >> 5;
  int len = lengths[b];
  len = (len < 1) ? 1 : ((len > TT) ? TT : len);
  u16* outp = Mb + (size_t)bt * 1024 + j * 32 + ih * 16;
  ushort8 w0, w1;
  float mx;
  if (t == 0 || t >= len) {
#pragma unroll
    for (int e = 0; e < 8; ++e) {
      w0[e] = ((ih * 16 + e) == j) ? (u16)0x3F80 : (u16)0;
      w1[e] = ((ih * 16 + 8 + e) == j) ? (u16)0x3F80 : (u16)0;
    }
    mx = 0.f;
  } else {
    int u = seq[b * TT + t - 1];
    float es2 = es[(size_t)bt * KK + j];  // log2 domain, row j of M^T
    const float4* p = (const float4*)(ltrans + u * KKK + j * KK + ih * 16);
    float4 q0 = p[0], q1 = p[1], q2 = p[2], q3 = p[3];
    float lg[16] = {q0.x, q0.y, q0.z, q0.w, q1.x, q1.y, q1.z, q1.w,
                    q2.x, q2.y, q2.z, q2.w, q3.x, q3.y, q3.z, q3.w};
#pragma unroll
    for (int e = 0; e < 16; ++e) lg[e] += es2;
    float m = lg[0];
#pragma unroll
    for (int e = 1; e < 16; ++e) m = fmaxf(m, lg[e]);
#pragma unroll
    for (int d = 1; d < 64; d <<= 1) m = fmaxf(m, __shfl_xor(m, d));
    mx = m;
#pragma unroll
    for (int e = 0; e < 8; ++e) {
      w0[e] = f2bf(fexp2(lg[e] - m));
      w1[e] = f2bf(fexp2(lg[8 + e] - m));
    }
  }
  *(ushort8*)(outp) = w0;
  *(ushort8*)(outp + 8) = w1;
  if (l == 0) msc[bt] = mx;
}

// ---------------------------------------------------------------------------
// Chunk product of 8 matrices via MFMA:  R = M7^T x ... x M0^T  (D-fragment)
// A-frag: lane l holds A[row=l&31][k=(l>>5)*8+e], e=0..7, per 16-k half.
// D-frag: lane l holds col l&31, rows (r&3)+8*(r>>2)+4*(l>>5).
__device__ __forceinline__ void chunk_product(const u16* mp, int l, int h,
                                              float* D) {
  int j = l & 31;
  short8 fr0[8], fr1[8];
#pragma unroll
  for (int s = 0; s < 8; ++s) {
    const u16* base = mp + s * 1024 + j * 32 + h * 8;
    fr0[s] = *(const short8*)(base);
    fr1[s] = *(const short8*)(base + 16);
  }
  // D = Identity
#pragma unroll
  for (int r = 0; r < 16; ++r) D[r] = 0.f;
  if (((j >> 2) & 1) == h) D[(j & 3) | ((j >> 3) << 2)] = 1.0f;

#pragma unroll
  for (int s = 0; s < 8; ++s) {
    // Convert running D (f32, D-layout) -> B-fragments (bf16):
    // B0 covers k=0..15, B1 covers k=16..31.
    float e0[8], e1[8];
#pragma unroll
    for (int i2 = 0; i2 < 4; ++i2) {
      float x0 = __shfl_xor(D[i2], 32);        // partner's rows
      float y0 = __shfl_xor(D[4 + i2], 32);
      e0[i2] = (h == 0) ? D[i2] : y0;          // k = 8h + i2
      e0[4 + i2] = (h == 0) ? x0 : D[4 + i2];  // k = 8h + 4 + i2
      float x1 = __shfl_xor(D[8 + i2], 32);
      float y1 = __shfl_xor(D[12 + i2], 32);
      e1[i2] = (h == 0) ? D[8 + i2] : y1;      // k = 16 + 8h + i2
      e1[4 + i2] = (h == 0) ? x1 : D[12 + i2]; // k = 16 + 8h + 4 + i2
    }
    short8 B0, B1;
#pragma unroll
    for (int e = 0; e < 8; ++e) {
      B0[e] = (short)f2bf(e0[e]);
      B1[e] = (short)f2bf(e1[e]);
    }
    f32x16 dn = {};
    dn = __builtin_amdgcn_mfma_f32_32x32x16_bf16(fr0[s], B0, dn, 0, 0, 0);
    dn = __builtin_amdgcn_mfma_f32_32x32x16_bf16(fr1[s], B1, dn, 0, 0, 0);
#pragma unroll
    for (int r = 0; r < 16; ++r) D[r] = dn[r];
  }
}

// ---------------------------------------------------------------------------
// K7: reduce 8 matrices -> 1 (normalized bf16 out + accumulated log2 scale)
__global__ __launch_bounds__(64) void k_prod(
    const u16* __restrict__ in, const float* __restrict__ insc,
    u16* __restrict__ out, float* __restrict__ outsc) {
  int c = blockIdx.x, l = threadIdx.x, h = l >> 5, j = l & 31;
  float D[16];
  chunk_product(in + (size_t)c * 8192, l, h, D);
  float mx = D[0];
#pragma unroll
  for (int r = 1; r < 16; ++r) mx = fmaxf(mx, D[r]);
#pragma unroll
  for (int d = 1; d < 64; d <<= 1) mx = fmaxf(mx, __shfl_xor(mx, d));
  float inv = 1.0f / mx;
  __shared__ float tmp[32 * 33];
#pragma unroll
  for (int r = 0; r < 16; ++r) {
    int row = (r & 3) + 8 * (r >> 2) + 4 * h;
    tmp[row * 33 + j] = D[r] * inv;
  }
  __syncthreads();
  ushort8 w0, w1;
#pragma unroll
  for (int e = 0; e < 8; ++e) {
    w0[e] = f2bf(tmp[j * 33 + h * 16 + e]);
    w1[e] = f2bf(tmp[j * 33 + h * 16 + 8 + e]);
  }
  u16* op = out + (size_t)c * 1024 + j * 32 + h * 16;
  *(ushort8*)op = w0;
  *(ushort8*)(op + 8) = w1;
  float si = (l < 8) ? insc[c * 8 + l] : 0.f;
#pragma unroll
  for (int d = 1; d < 64; d <<= 1) si += __shfl_xor(si, d);
  if (l == 0) outsc[c] = flog2(mx) + si;
}

// ---------------------------------------------------------------------------
// K8: final level: product of 8, then NLL = -ln2*(log2(sum_i a0_i*colsum_i)
//     + a0max + total scale)
__global__ __launch_bounds__(64) void k_final(
    const u16* __restrict__ C2, const float* __restrict__ s2,
    const float* __restrict__ es, const float* __restrict__ init_logits,
    float* __restrict__ out) {
  int b = blockIdx.x, l = threadIdx.x, h = l >> 5, j = l & 31;
  float D[16];
  chunk_product(C2 + (size_t)b * 8192, l, h, D);
  // alpha0 (log2 domain)
  float il = init_logits[j] * INV_LN2;
  float m0 = il;
#pragma unroll
  for (int d = 1; d < 32; d <<= 1) m0 = fmaxf(m0, __shfl_xor(m0, d));
  float s0 = fexp2(il - m0);
#pragma unroll
  for (int d = 1; d < 32; d <<= 1) s0 += __shfl_xor(s0, d);
  float lse0 = m0 + flog2(s0);
  float z = il - lse0 + es[(size_t)b * TT * KK + j];
  float am = z;
#pragma unroll
  for (int d = 1; d < 32; d <<= 1) am = fmaxf(am, __shfl_xor(am, d));
  float a0 = fexp2(z - am);
  // sum_j v[j] = sum_cols a0[col] * colsum(col); each lane owns half a column
  float colsum = 0.f;
#pragma unroll
  for (int r = 0; r < 16; ++r) colsum += D[r];
  float p = a0 * colsum;
#pragma unroll
  for (int d = 1; d < 64; d <<= 1) p += __shfl_xor(p, d);
  float si = (l < 8) ? s2[b * 8 + l] : 0.f;
#pragma unroll
  for (int d = 1; d < 64; d <<= 1) si += __shfl_xor(si, d);
  if (l == 0) out[b] = -LN2 * (flog2(p) + am + si);
}

// ---------------------------------------------------------------------------
// Fallback sequential forward recursion (used only if ws too small)
__global__ __launch_bounds__(64) void k_forward(
    const int* __restrict__ seq, const int* __restrict__ lengths,
    const float* __restrict__ ltrans, const float* __restrict__ es,
    const float* __restrict__ init_logits, float* __restrict__ out) {
  int b = blockIdx.x;
  int l = threadIdx.x;
  int j = l & 31, half = l >> 5;
  __shared__ int sb_s[TT];
#pragma unroll
  for (int r = 0; r < 8; ++r) sb_s[r * 64 + l] = seq[b * TT + r * 64 + l];
  __syncthreads();
  const float* esb = es + b * TT * KK;
  float il = init_logits[j] * INV_LN2;
  float m0 = il;
#pragma unroll
  for (int d = 1; d < 32; d <<= 1) m0 = fmaxf(m0, __shfl_xor(m0, d));
  float s0 = fexp2(il - m0);
#pragma unroll
  for (int d = 1; d < 32; d <<= 1) s0 += __shfl_xor(s0, d);
  float lse0 = m0 + flog2(s0);
  int len = lengths[b];
  if (len > TT) len = TT;
  if (len < 1) len = 1;
  float a = il - lse0 + esb[j];
  float lt1[16], lt2[16], lt0[16];
  float es0v = 0.f, es1v = 0.f, es2v = 0.f;
#define LOADSTEP(LT, ES, tt)                                                \
  {                                                                         \
    int u = sb_s[(tt)-1];                                                   \
    const float4* p4 = (const float4*)(ltrans + u * KKK + j * KK + half * 16); \
    float4 q0 = p4[0], q1 = p4[1], q2 = p4[2], q3 = p4[3];                  \
    LT[0] = q0.x; LT[1] = q0.y; LT[2] = q0.z; LT[3] = q0.w;                 \
    LT[4] = q1.x; LT[5] = q1.y; LT[6] = q1.z; LT[7] = q1.w;                 \
    LT[8] = q2.x; LT[9] = q2.y; LT[10] = q2.z; LT[11] = q2.w;               \
    LT[12] = q3.x; LT[13] = q3.y; LT[14] = q3.z; LT[15] = q3.w;             \
    ES = esb[(tt)*KK + j];                                                  \
  }
#define COMPUTE(LT, ES)                                                     \
  {                                                                         \
    float vv[16];                                                           \
    _Pragma("unroll") for (int r = 0; r < 16; ++r)                          \
        vv[r] = __shfl(a, half * 16 + r, 64) + LT[r];                       \
    float m8[8];                                                            \
    _Pragma("unroll") for (int r = 0; r < 8; ++r)                           \
        m8[r] = fmaxf(vv[2 * r], vv[2 * r + 1]);                            \
    float m4[4];                                                            \
    _Pragma("unroll") for (int r = 0; r < 4; ++r)                           \
        m4[r] = fmaxf(m8[2 * r], m8[2 * r + 1]);                            \
    float m = fmaxf(fmaxf(m4[0], m4[1]), fmaxf(m4[2], m4[3]));              \
    float s8[8];                                                            \
    _Pragma("unroll") for (int r = 0; r < 8; ++r)                           \
        s8[r] = fexp2(vv[2 * r] - m) + fexp2(vv[2 * r + 1] - m);            \
    float s4[4];                                                            \
    _Pragma("unroll") for (int r = 0; r < 4; ++r) s4[r] = s8[2 * r] + s8[2 * r + 1]; \
    float s = (s4[0] + s4[1]) + (s4[2] + s4[3]);                            \
    float mo = __shfl_xor(m, 32);                                           \
    float so = __shfl_xor(s, 32);                                           \
    float mm = fmaxf(m, mo);                                                \
    float ss = s * fexp2(m - mm) + so * fexp2(mo - mm);                     \
    a = mm + flog2(ss) + ES;                                                \
  }
  if (len > 1) LOADSTEP(lt1, es1v, 1);
  if (len > 2) LOADSTEP(lt2, es2v, 2);
  int t = 1;
  while (t < len) {
    if (t + 2 < len) LOADSTEP(lt0, es0v, t + 2);
    COMPUTE(lt1, es1v);
    ++t;
    if (t >= len) break;
    if (t + 2 < len) LOADSTEP(lt1, es1v, t + 2);
    COMPUTE(lt2, es2v);
    ++t;
    if (t >= len) break;
    if (t + 2 < len) LOADSTEP(lt2, es2v, t + 2);
    COMPUTE(lt0, es0v);
    ++t;
  }
  float mf = a;
#pragma unroll
  for (int d = 1; d < 32; d <<= 1) mf = fmaxf(mf, __shfl_xor(mf, d));
  float sf = fexp2(a - mf);
#pragma unroll
  for (int d = 1; d < 32; d <<= 1) sf += __shfl_xor(sf, d);
  if (l == 0) out[b] = -LN2 * (mf + flog2(sf));
}

// ---------------------------------------------------------------------------
extern "C" void kernel_launch(void* const* d_in, const int* in_sizes, int n_in,
                              void* d_out, int out_size, void* d_ws,
                              size_t ws_size, hipStream_t stream) {
  const int* seq = (const int*)d_in[0];
  const int* lengths = (const int*)d_in[1];
  const float* emb = (const float*)d_in[2];
  const float* W1 = (const float*)d_in[3];
  const float* b1 = (const float*)d_in[4];
  const float* W2 = (const float*)d_in[5];
  const float* b2 = (const float*)d_in[6];
  const float* E1 = (const float*)d_in[7];
  const float* e1 = (const float*)d_in[8];
  const float* E2 = (const float*)d_in[9];
  const float* e2 = (const float*)d_in[10];
  const float* init_logits = (const float*)d_in[11];
  float* out = (float*)d_out;

  char* wsb = (char*)d_ws;
  float* h1_tab = (float*)wsb;              // 512*128
  float* h2_tab = h1_tab + 512 * 128;       // 512*128
  float* ltrans = h2_tab + 512 * 128;       // 512*1024 (transposed, log2)
  float* E2p = ltrans + 512 * 1024;         // 16384*128
  float* part_m = E2p + 16384 * 128;        // 512*32*8
  float* part_s = part_m + 512 * 32 * 8;    // 512*32*8
  float* lse_tab = part_s + 512 * 32 * 8;   // 512*32
  float* es = lse_tab + 512 * 32;           // 16*512*32 (log2 domain)
  // scan buffers (bytes from start): old front-end ends at 13,172,736 B
  const size_t OLD_END = 13172736;
  u16* Mb = (u16*)(wsb + OLD_END);                         // 8192*1024 bf16 = 16,777,216 B
  float* msc = (float*)(wsb + OLD_END + 16777216);         // 8192 f32 = 32,768 B
  u16* C1 = (u16*)(wsb + OLD_END + 16809984);              // 1024*1024 bf16 = 2,097,152 B
  float* s1 = (float*)(wsb + OLD_END + 18907136);          // 1024 f32 = 4,096 B
  u16* C2 = (u16*)(wsb + OLD_END + 18911232);              // 128*1024 bf16 = 262,144 B
  float* s2 = (float*)(wsb + OLD_END + 19173376);          // 128 f32 = 512 B
  const size_t NEED = OLD_END + 19173888;                  // 32,346,624 B

  k_hidden<<<512, 128, 0, stream>>>(emb, W1, b1, E1, e1, h1_tab, h2_tab);
  k_transpose<<<8192, 256, 0, stream>>>(E2, E2p);
  k_trans<<<512, 256, 0, stream>>>(h1_tab, W2, b2, ltrans);
  k_emit_gemm<<<dim3(256, 8), 256, 0, stream>>>(h2_tab, E2, e2, part_m, part_s);
  k_lsecomb<<<64, 256, 0, stream>>>(part_m, part_s, lse_tab);
  k_es<<<8192, 64, 0, stream>>>(seq, h2_tab, E2p, e2, lse_tab, es);

  if (ws_size >= NEED) {
    k_mat<<<8192, 64, 0, stream>>>(seq, lengths, ltrans, es, Mb, msc);
    k_prod<<<1024, 64, 0, stream>>>(Mb, msc, C1, s1);
    k_prod<<<128, 64, 0, stream>>>(C1, s1, C2, s2);
    k_final<<<16, 64, 0, stream>>>(C2, s2, es, init_logits, out);
  } else {
    k_forward<<<16, 64, 0, stream>>>(seq, lengths, ltrans, es, init_logits, out);
  }
}

// Round 4
// 113.160 us; speedup vs baseline: 3.6117x; 1.1152x over previous
//
#include <hip/hip_runtime.h>
#include <hip/hip_bf16.h>

// Problem constants
#define BB 16
#define TT 512
#define KK 32
#define VV 512
#define DD 64
#define HH 128
#define KV (KK*VV)   // 16384
#define KKK (KK*KK)  // 1024

#define INV_LN2 1.4426950408889634f
#define LN2 0.6931471805599453f

typedef unsigned short u16;
typedef __attribute__((ext_vector_type(8))) short short8;
typedef __attribute__((ext_vector_type(8))) unsigned short ushort8;
typedef __attribute__((ext_vector_type(16))) float f32x16;

__device__ __forceinline__ float fexp2(float x) { return __builtin_amdgcn_exp2f(x); }
__device__ __forceinline__ float flog2(float x) { return __builtin_amdgcn_logf(x); }

// float -> bf16 bits, round-nearest-even (finite inputs only)
__device__ __forceinline__ u16 f2bf(float f) {
  unsigned u = __builtin_bit_cast(unsigned, f);
  u += 0x7FFFu + ((u >> 16) & 1u);
  return (u16)(u >> 16);
}

// ---------------------------------------------------------------------------
// K1: per-token hidden activations  h1 = relu(emb@W1+b1), h2 = relu(emb@E1+e1)
__global__ __launch_bounds__(128) void k_hidden(
    const float* __restrict__ emb, const float* __restrict__ W1,
    const float* __restrict__ b1, const float* __restrict__ E1,
    const float* __restrict__ e1, float* __restrict__ h1_tab,
    float* __restrict__ h2_tab, u16* __restrict__ h2b, int do_bf) {
  __shared__ float x[DD];
  int u = blockIdx.x, h = threadIdx.x;
  if (h < DD) x[h] = emb[u * DD + h];
  __syncthreads();
  float a1 = b1[h], a2 = e1[h];
#pragma unroll
  for (int d = 0; d < DD; ++d) {
    float xv = x[d];
    a1 += xv * W1[d * HH + h];
    a2 += xv * E1[d * HH + h];
  }
  float r2 = fmaxf(a2, 0.f);
  h1_tab[u * HH + h] = fmaxf(a1, 0.f);
  h2_tab[u * HH + h] = r2;
  if (do_bf) h2b[u * HH + h] = f2bf(r2);
}

// ---------------------------------------------------------------------------
// K0: transpose E2 (128 x 16384) -> E2p (16384 x 128) fp32 + bf16 copy
__global__ __launch_bounds__(256) void k_transpose(
    const float* __restrict__ E2, float* __restrict__ E2p,
    u16* __restrict__ E2bT, int do_bf) {
  int idx = blockIdx.x * 256 + threadIdx.x;  // over 128*16384
  int h = idx >> 14, col = idx & 16383;
  float v = E2[idx];
  E2p[col * HH + h] = v;
  if (do_bf) E2bT[col * HH + h] = f2bf(v);
}

// ---------------------------------------------------------------------------
// K2: per-token transition table, row-log-softmaxed, stored TRANSPOSED and
// scaled to log2 domain: ltrans_T[u*1024 + j*32 + i] = (lg[i][j]-lse[i])/ln2
__global__ __launch_bounds__(256) void k_trans(
    const float* __restrict__ h1_tab, const float* __restrict__ W2,
    const float* __restrict__ b2, float* __restrict__ ltrans) {
  __shared__ float h1s[HH];
  __shared__ float lg[KK * 33];
  __shared__ float lse[KK];
  int u = blockIdx.x, tid = threadIdx.x;
  if (tid < HH) h1s[tid] = h1_tab[u * HH + tid];
  __syncthreads();
  float acc[4];
#pragma unroll
  for (int r = 0; r < 4; ++r) acc[r] = b2[tid + r * 256];
  for (int h = 0; h < HH; ++h) {
    float hv = h1s[h];
#pragma unroll
    for (int r = 0; r < 4; ++r) acc[r] += hv * W2[h * KKK + tid + r * 256];
  }
#pragma unroll
  for (int r = 0; r < 4; ++r) {
    int c = tid + r * 256;                 // c = i*32 + j
    lg[(c >> 5) * 33 + (c & 31)] = acc[r] * INV_LN2;
  }
  __syncthreads();
  if (tid < KK) {
    float m = -1e30f;
    for (int jj = 0; jj < KK; ++jj) m = fmaxf(m, lg[tid * 33 + jj]);
    float s = 0.f;
    for (int jj = 0; jj < KK; ++jj) s += fexp2(lg[tid * 33 + jj] - m);
    lse[tid] = m + flog2(s);
  }
  __syncthreads();
#pragma unroll
  for (int r = 0; r < 4; ++r) {
    int c = tid + r * 256;                 // c = j*32 + i (transposed layout)
    int jj = c >> 5, ii = c & 31;
    ltrans[u * KKK + jj * KK + ii] = lg[ii * 33 + jj] - lse[ii];
  }
}

// ---------------------------------------------------------------------------
// K3-new: emission GEMM via MFMA + fused LSE over V.
// grid: (32 k-groups, 16 row-tiles), block 256 (4 waves).
// Each wave: 4 col-tiles of 32 cols, K=128 via 8x mfma_f32_32x32x16_bf16.
// Output: lse2_tab[u*32+k] (log2 domain).
__global__ __launch_bounds__(256) void k_emit_lse(
    const u16* __restrict__ h2b, const u16* __restrict__ E2bT,
    const float* __restrict__ e2, float* __restrict__ lse2_tab) {
  int k = blockIdx.x;        // 0..31
  int u0 = blockIdx.y * 32;  // row tile base
  int tid = threadIdx.x;
  int w = tid >> 6, l = tid & 63;
  int h = l >> 5, j = l & 31;
  __shared__ float lm[4 * 32], ls[4 * 32];

  // A-fragments: rows u0+j, k-halves
  short8 A[8];
#pragma unroll
  for (int kh = 0; kh < 8; ++kh)
    A[kh] = *(const short8*)(h2b + (u0 + j) * HH + kh * 16 + h * 8);

  float m[16], s[16];
#pragma unroll
  for (int r = 0; r < 16; ++r) { m[r] = -1e30f; s[r] = 0.f; }

#pragma unroll
  for (int c = 0; c < 4; ++c) {
    int ct = w * 4 + c;
    int col = k * 512 + ct * 32 + j;       // global column
    const u16* bp = E2bT + (size_t)col * HH + h * 8;
    f32x16 acc = {};
#pragma unroll
    for (int kh = 0; kh < 8; ++kh) {
      short8 Bf = *(const short8*)(bp + kh * 16);
      acc = __builtin_amdgcn_mfma_f32_32x32x16_bf16(A[kh], Bf, acc, 0, 0, 0);
    }
    float e2v = e2[col] * INV_LN2;
#pragma unroll
    for (int r = 0; r < 16; ++r) {
      float v2 = acc[r] * INV_LN2 + e2v;
      float mn = fmaxf(m[r], v2);
      s[r] = s[r] * fexp2(m[r] - mn) + fexp2(v2 - mn);
      m[r] = mn;
    }
  }
  // intra-half reduce over 32 lanes (cols)
#pragma unroll
  for (int r = 0; r < 16; ++r) {
#pragma unroll
    for (int d = 1; d < 32; d <<= 1) {
      float mo = __shfl_xor(m[r], d);
      float so = __shfl_xor(s[r], d);
      float mn = fmaxf(m[r], mo);
      s[r] = s[r] * fexp2(m[r] - mn) + so * fexp2(mo - mn);
      m[r] = mn;
    }
  }
  if (j == 0) {
#pragma unroll
    for (int r = 0; r < 16; ++r) {
      int row = (r & 3) + 8 * (r >> 2) + 4 * h;
      lm[w * 32 + row] = m[r];
      ls[w * 32 + row] = s[r];
    }
  }
  __syncthreads();
  if (tid < 32) {
    float mm = lm[tid], ss = ls[tid];
#pragma unroll
    for (int w2 = 1; w2 < 4; ++w2) {
      float mo = lm[w2 * 32 + tid], so = ls[w2 * 32 + tid];
      float mn = fmaxf(mm, mo);
      ss = ss * fexp2(mm - mn) + so * fexp2(mo - mn);
      mm = mn;
    }
    lse2_tab[(u0 + tid) * KK + k] = mm + flog2(ss);
  }
}

// ---------------------------------------------------------------------------
// K3-fallback: emission GEMM (512 x 16384) with fused per-tile partials
__global__ __launch_bounds__(256) void k_emit_gemm(
    const float* __restrict__ h2_tab, const float* __restrict__ E2,
    const float* __restrict__ e2, float* __restrict__ part_m,
    float* __restrict__ part_s) {
  __shared__ float As[64 * 65];
  __shared__ float Bs[64 * 64];
  int bn = blockIdx.x, bu = blockIdx.y;
  int tid = threadIdx.x;
  int tx = tid & 15, ty = tid >> 4;
  float accv[4][4] = {{0.f}};
  for (int kt = 0; kt < 2; ++kt) {
    __syncthreads();
#pragma unroll
    for (int r = 0; r < 16; ++r) {
      int idx = r * 256 + tid;
      int row = idx >> 6, kk = idx & 63;
      As[row * 65 + kk] = h2_tab[(bu * 64 + row) * HH + kt * 64 + kk];
      Bs[idx] = E2[(kt * 64 + row) * KV + bn * 64 + kk];
    }
    __syncthreads();
    for (int kk = 0; kk < 64; ++kk) {
      float a[4], bv[4];
#pragma unroll
      for (int i = 0; i < 4; ++i) a[i] = As[(ty * 4 + i) * 65 + kk];
#pragma unroll
      for (int jj = 0; jj < 4; ++jj) bv[jj] = Bs[kk * 64 + tx * 4 + jj];
#pragma unroll
      for (int i = 0; i < 4; ++i)
#pragma unroll
        for (int jj = 0; jj < 4; ++jj) accv[i][jj] += a[i] * bv[jj];
    }
  }
  float e2v[4];
#pragma unroll
  for (int jj = 0; jj < 4; ++jj) e2v[jj] = e2[bn * 64 + tx * 4 + jj];
#pragma unroll
  for (int i = 0; i < 4; ++i)
#pragma unroll
    for (int jj = 0; jj < 4; ++jj) accv[i][jj] += e2v[jj];

  int kcol = bn >> 3, tseg = bn & 7;
#pragma unroll
  for (int i = 0; i < 4; ++i) {
    float m = fmaxf(fmaxf(accv[i][0], accv[i][1]), fmaxf(accv[i][2], accv[i][3]));
#pragma unroll
    for (int d = 1; d < 16; d <<= 1) m = fmaxf(m, __shfl_xor(m, d));
    float s = 0.f;
#pragma unroll
    for (int jj = 0; jj < 4; ++jj) s += __expf(accv[i][jj] - m);
#pragma unroll
    for (int d = 1; d < 16; d <<= 1) s += __shfl_xor(s, d);
    if (tx == 0) {
      int u = bu * 64 + ty * 4 + i;
      int pi = (u * KK + kcol) * 8 + tseg;
      part_m[pi] = m;
      part_s[pi] = s;
    }
  }
}

// ---------------------------------------------------------------------------
// K4-fallback: combine 8 tile partials -> lse2_tab (512*32), log2 domain out
__global__ __launch_bounds__(256) void k_lsecomb(
    const float* __restrict__ pm, const float* __restrict__ ps,
    float* __restrict__ lse_tab) {
  int i = blockIdx.x * 256 + threadIdx.x;  // 16384
  float m = -1e30f, s = 0.f;
#pragma unroll
  for (int t = 0; t < 8; ++t) {
    float mm = pm[i * 8 + t], ss = ps[i * 8 + t];
    float nm = fmaxf(m, mm);
    s = s * __expf(m - nm) + ss * __expf(mm - nm);
    m = nm;
  }
  lse_tab[i] = (m + __logf(s)) * INV_LN2;
}

// ---------------------------------------------------------------------------
// K5: emission scores (log2 domain); lse2_tab is log2 domain
__global__ __launch_bounds__(64) void k_es(
    const int* __restrict__ seq, const float* __restrict__ h2_tab,
    const float* __restrict__ E2p, const float* __restrict__ e2,
    const float* __restrict__ lse2_tab, float* __restrict__ es) {
  int bt = blockIdx.x;  // 0..8191
  int b = bt >> 9, t = bt & 511;
  int l = threadIdx.x;
  int k = l >> 1, half = l & 1;
  int y = seq[b * TT + t];
  int u = (t == 0) ? 0 : seq[b * TT + t - 1];
  const float4* hv = (const float4*)(h2_tab + u * HH + half * 64);
  const float4* ev = (const float4*)(E2p + (k * VV + y) * HH + half * 64);
  float acc = 0.f;
#pragma unroll
  for (int r = 0; r < 16; ++r) {
    float4 a = hv[r], bq = ev[r];
    acc += a.x * bq.x + a.y * bq.y + a.z * bq.z + a.w * bq.w;
  }
  acc += __shfl_xor(acc, 1);
  if (half == 0)
    es[bt * KK + k] = (acc + e2[k * VV + y]) * INV_LN2 - lse2_tab[u * KK + k];
}

// ---------------------------------------------------------------------------
// K6: build normalized step matrices M_t^T in bf16 (row-major 32x32 per (b,t))
__global__ __launch_bounds__(64) void k_mat(
    const int* __restrict__ seq, const int* __restrict__ lengths,
    const float* __restrict__ ltrans, const float* __restrict__ es,
    u16* __restrict__ Mb, float* __restrict__ msc) {
  int bt = blockIdx.x;
  int b = bt >> 9, t = bt & 511;
  int l = threadIdx.x;
  int j = l & 31, ih = l >> 5;
  int len = lengths[b];
  len = (len < 1) ? 1 : ((len > TT) ? TT : len);
  u16* outp = Mb + (size_t)bt * 1024 + j * 32 + ih * 16;
  ushort8 w0, w1;
  float mx;
  if (t == 0 || t >= len) {
#pragma unroll
    for (int e = 0; e < 8; ++e) {
      w0[e] = ((ih * 16 + e) == j) ? (u16)0x3F80 : (u16)0;
      w1[e] = ((ih * 16 + 8 + e) == j) ? (u16)0x3F80 : (u16)0;
    }
    mx = 0.f;
  } else {
    int u = seq[b * TT + t - 1];
    float es2 = es[(size_t)bt * KK + j];  // log2 domain, row j of M^T
    const float4* p = (const float4*)(ltrans + u * KKK + j * KK + ih * 16);
    float4 q0 = p[0], q1 = p[1], q2 = p[2], q3 = p[3];
    float lg[16] = {q0.x, q0.y, q0.z, q0.w, q1.x, q1.y, q1.z, q1.w,
                    q2.x, q2.y, q2.z, q2.w, q3.x, q3.y, q3.z, q3.w};
#pragma unroll
    for (int e = 0; e < 16; ++e) lg[e] += es2;
    float m = lg[0];
#pragma unroll
    for (int e = 1; e < 16; ++e) m = fmaxf(m, lg[e]);
#pragma unroll
    for (int d = 1; d < 64; d <<= 1) m = fmaxf(m, __shfl_xor(m, d));
    mx = m;
#pragma unroll
    for (int e = 0; e < 8; ++e) {
      w0[e] = f2bf(fexp2(lg[e] - m));
      w1[e] = f2bf(fexp2(lg[8 + e] - m));
    }
  }
  *(ushort8*)(outp) = w0;
  *(ushort8*)(outp + 8) = w1;
  if (l == 0) msc[bt] = mx;
}

// ---------------------------------------------------------------------------
// Chunk product of 8 matrices via MFMA:  R = M7^T x ... x M0^T  (D-fragment)
__device__ __forceinline__ void chunk_product(const u16* mp, int l, int h,
                                              float* D) {
  int j = l & 31;
  short8 fr0[8], fr1[8];
#pragma unroll
  for (int s = 0; s < 8; ++s) {
    const u16* base = mp + s * 1024 + j * 32 + h * 8;
    fr0[s] = *(const short8*)(base);
    fr1[s] = *(const short8*)(base + 16);
  }
#pragma unroll
  for (int r = 0; r < 16; ++r) D[r] = 0.f;
  if (((j >> 2) & 1) == h) D[(j & 3) | ((j >> 3) << 2)] = 1.0f;

#pragma unroll
  for (int s = 0; s < 8; ++s) {
    float e0[8], e1[8];
#pragma unroll
    for (int i2 = 0; i2 < 4; ++i2) {
      float x0 = __shfl_xor(D[i2], 32);
      float y0 = __shfl_xor(D[4 + i2], 32);
      e0[i2] = (h == 0) ? D[i2] : y0;
      e0[4 + i2] = (h == 0) ? x0 : D[4 + i2];
      float x1 = __shfl_xor(D[8 + i2], 32);
      float y1 = __shfl_xor(D[12 + i2], 32);
      e1[i2] = (h == 0) ? D[8 + i2] : y1;
      e1[4 + i2] = (h == 0) ? x1 : D[12 + i2];
    }
    short8 B0, B1;
#pragma unroll
    for (int e = 0; e < 8; ++e) {
      B0[e] = (short)f2bf(e0[e]);
      B1[e] = (short)f2bf(e1[e]);
    }
    f32x16 dn = {};
    dn = __builtin_amdgcn_mfma_f32_32x32x16_bf16(fr0[s], B0, dn, 0, 0, 0);
    dn = __builtin_amdgcn_mfma_f32_32x32x16_bf16(fr1[s], B1, dn, 0, 0, 0);
#pragma unroll
    for (int r = 0; r < 16; ++r) D[r] = dn[r];
  }
}

// ---------------------------------------------------------------------------
// K7: reduce 8 matrices -> 1 (normalized bf16 out + accumulated log2 scale)
__global__ __launch_bounds__(64) void k_prod(
    const u16* __restrict__ in, const float* __restrict__ insc,
    u16* __restrict__ out, float* __restrict__ outsc) {
  int c = blockIdx.x, l = threadIdx.x, h = l >> 5, j = l & 31;
  float D[16];
  chunk_product(in + (size_t)c * 8192, l, h, D);
  float mx = D[0];
#pragma unroll
  for (int r = 1; r < 16; ++r) mx = fmaxf(mx, D[r]);
#pragma unroll
  for (int d = 1; d < 64; d <<= 1) mx = fmaxf(mx, __shfl_xor(mx, d));
  float inv = 1.0f / mx;
  __shared__ float tmp[32 * 33];
#pragma unroll
  for (int r = 0; r < 16; ++r) {
    int row = (r & 3) + 8 * (r >> 2) + 4 * h;
    tmp[row * 33 + j] = D[r] * inv;
  }
  __syncthreads();
  ushort8 w0, w1;
#pragma unroll
  for (int e = 0; e < 8; ++e) {
    w0[e] = f2bf(tmp[j * 33 + h * 16 + e]);
    w1[e] = f2bf(tmp[j * 33 + h * 16 + 8 + e]);
  }
  u16* op = out + (size_t)c * 1024 + j * 32 + h * 16;
  *(ushort8*)op = w0;
  *(ushort8*)(op + 8) = w1;
  float si = (l < 8) ? insc[c * 8 + l] : 0.f;
#pragma unroll
  for (int d = 1; d < 64; d <<= 1) si += __shfl_xor(si, d);
  if (l == 0) outsc[c] = flog2(mx) + si;
}

// ---------------------------------------------------------------------------
// K8: final level: product of 8, then NLL
__global__ __launch_bounds__(64) void k_final(
    const u16* __restrict__ C2, const float* __restrict__ s2,
    const float* __restrict__ es, const float* __restrict__ init_logits,
    float* __restrict__ out) {
  int b = blockIdx.x, l = threadIdx.x, h = l >> 5, j = l & 31;
  float D[16];
  chunk_product(C2 + (size_t)b * 8192, l, h, D);
  float il = init_logits[j] * INV_LN2;
  float m0 = il;
#pragma unroll
  for (int d = 1; d < 32; d <<= 1) m0 = fmaxf(m0, __shfl_xor(m0, d));
  float s0 = fexp2(il - m0);
#pragma unroll
  for (int d = 1; d < 32; d <<= 1) s0 += __shfl_xor(s0, d);
  float lse0 = m0 + flog2(s0);
  float z = il - lse0 + es[(size_t)b * TT * KK + j];
  float am = z;
#pragma unroll
  for (int d = 1; d < 32; d <<= 1) am = fmaxf(am, __shfl_xor(am, d));
  float a0 = fexp2(z - am);
  float colsum = 0.f;
#pragma unroll
  for (int r = 0; r < 16; ++r) colsum += D[r];
  float p = a0 * colsum;
#pragma unroll
  for (int d = 1; d < 64; d <<= 1) p += __shfl_xor(p, d);
  float si = (l < 8) ? s2[b * 8 + l] : 0.f;
#pragma unroll
  for (int d = 1; d < 64; d <<= 1) si += __shfl_xor(si, d);
  if (l == 0) out[b] = -LN2 * (flog2(p) + am + si);
}

// ---------------------------------------------------------------------------
// Fallback sequential forward recursion (used only if ws too small)
__global__ __launch_bounds__(64) void k_forward(
    const int* __restrict__ seq, const int* __restrict__ lengths,
    const float* __restrict__ ltrans, const float* __restrict__ es,
    const float* __restrict__ init_logits, float* __restrict__ out) {
  int b = blockIdx.x;
  int l = threadIdx.x;
  int j = l & 31, half = l >> 5;
  __shared__ int sb_s[TT];
#pragma unroll
  for (int r = 0; r < 8; ++r) sb_s[r * 64 + l] = seq[b * TT + r * 64 + l];
  __syncthreads();
  const float* esb = es + b * TT * KK;
  float il = init_logits[j] * INV_LN2;
  float m0 = il;
#pragma unroll
  for (int d = 1; d < 32; d <<= 1) m0 = fmaxf(m0, __shfl_xor(m0, d));
  float s0 = fexp2(il - m0);
#pragma unroll
  for (int d = 1; d < 32; d <<= 1) s0 += __shfl_xor(s0, d);
  float lse0 = m0 + flog2(s0);
  int len = lengths[b];
  if (len > TT) len = TT;
  if (len < 1) len = 1;
  float a = il - lse0 + esb[j];
  float lt1[16], lt2[16], lt0[16];
  float es0v = 0.f, es1v = 0.f, es2v = 0.f;
#define LOADSTEP(LT, ES, tt)                                                \
  {                                                                         \
    int u = sb_s[(tt)-1];                                                   \
    const float4* p4 = (const float4*)(ltrans + u * KKK + j * KK + half * 16); \
    float4 q0 = p4[0], q1 = p4[1], q2 = p4[2], q3 = p4[3];                  \
    LT[0] = q0.x; LT[1] = q0.y; LT[2] = q0.z; LT[3] = q0.w;                 \
    LT[4] = q1.x; LT[5] = q1.y; LT[6] = q1.z; LT[7] = q1.w;                 \
    LT[8] = q2.x; LT[9] = q2.y; LT[10] = q2.z; LT[11] = q2.w;               \
    LT[12] = q3.x; LT[13] = q3.y; LT[14] = q3.z; LT[15] = q3.w;             \
    ES = esb[(tt)*KK + j];                                                  \
  }
#define COMPUTE(LT, ES)                                                     \
  {                                                                         \
    float vv[16];                                                           \
    _Pragma("unroll") for (int r = 0; r < 16; ++r)                          \
        vv[r] = __shfl(a, half * 16 + r, 64) + LT[r];                       \
    float m8[8];                                                            \
    _Pragma("unroll") for (int r = 0; r < 8; ++r)                           \
        m8[r] = fmaxf(vv[2 * r], vv[2 * r + 1]);                            \
    float m4[4];                                                            \
    _Pragma("unroll") for (int r = 0; r < 4; ++r)                           \
        m4[r] = fmaxf(m8[2 * r], m8[2 * r + 1]);                            \
    float m = fmaxf(fmaxf(m4[0], m4[1]), fmaxf(m4[2], m4[3]));              \
    float s8[8];                                                            \
    _Pragma("unroll") for (int r = 0; r < 8; ++r)                           \
        s8[r] = fexp2(vv[2 * r] - m) + fexp2(vv[2 * r + 1] - m);            \
    float s4[4];                                                            \
    _Pragma("unroll") for (int r = 0; r < 4; ++r) s4[r] = s8[2 * r] + s8[2 * r + 1]; \
    float s = (s4[0] + s4[1]) + (s4[2] + s4[3]);                            \
    float mo = __shfl_xor(m, 32);                                           \
    float so = __shfl_xor(s, 32);                                           \
    float mm = fmaxf(m, mo);                                                \
    float ss = s * fexp2(m - mm) + so * fexp2(mo - mm);                     \
    a = mm + flog2(ss) + ES;                                                \
  }
  if (len > 1) LOADSTEP(lt1, es1v, 1);
  if (len > 2) LOADSTEP(lt2, es2v, 2);
  int t = 1;
  while (t < len) {
    if (t + 2 < len) LOADSTEP(lt0, es0v, t + 2);
    COMPUTE(lt1, es1v);
    ++t;
    if (t >= len) break;
    if (t + 2 < len) LOADSTEP(lt1, es1v, t + 2);
    COMPUTE(lt2, es2v);
    ++t;
    if (t >= len) break;
    if (t + 2 < len) LOADSTEP(lt2, es2v, t + 2);
    COMPUTE(lt0, es0v);
    ++t;
  }
  float mf = a;
#pragma unroll
  for (int d = 1; d < 32; d <<= 1) mf = fmaxf(mf, __shfl_xor(mf, d));
  float sf = fexp2(a - mf);
#pragma unroll
  for (int d = 1; d < 32; d <<= 1) sf += __shfl_xor(sf, d);
  if (l == 0) out[b] = -LN2 * (mf + flog2(sf));
}

// ---------------------------------------------------------------------------
extern "C" void kernel_launch(void* const* d_in, const int* in_sizes, int n_in,
                              void* d_out, int out_size, void* d_ws,
                              size_t ws_size, hipStream_t stream) {
  const int* seq = (const int*)d_in[0];
  const int* lengths = (const int*)d_in[1];
  const float* emb = (const float*)d_in[2];
  const float* W1 = (const float*)d_in[3];
  const float* b1 = (const float*)d_in[4];
  const float* W2 = (const float*)d_in[5];
  const float* b2 = (const float*)d_in[6];
  const float* E1 = (const float*)d_in[7];
  const float* e1 = (const float*)d_in[8];
  const float* E2 = (const float*)d_in[9];
  const float* e2 = (const float*)d_in[10];
  const float* init_logits = (const float*)d_in[11];
  float* out = (float*)d_out;

  char* wsb = (char*)d_ws;
  float* h1_tab = (float*)wsb;              // 512*128
  float* h2_tab = h1_tab + 512 * 128;       // 512*128
  float* ltrans = h2_tab + 512 * 128;       // 512*1024 (transposed, log2)
  float* E2p = ltrans + 512 * 1024;         // 16384*128
  float* part_m = E2p + 16384 * 128;        // 512*32*8
  float* part_s = part_m + 512 * 32 * 8;    // 512*32*8
  float* lse_tab = part_s + 512 * 32 * 8;   // 512*32 (log2 domain)
  float* es = lse_tab + 512 * 32;           // 16*512*32 (log2 domain)
  const size_t OLD_END = 13172736;
  u16* Mb = (u16*)(wsb + OLD_END);                         // 16,777,216 B
  float* msc = (float*)(wsb + OLD_END + 16777216);         // 32,768 B
  u16* C1 = (u16*)(wsb + OLD_END + 16809984);              // 2,097,152 B
  float* s1 = (float*)(wsb + OLD_END + 18907136);          // 4,096 B
  u16* C2 = (u16*)(wsb + OLD_END + 18911232);              // 262,144 B
  float* s2 = (float*)(wsb + OLD_END + 19173376);          // 512 B
  const size_t NEED = OLD_END + 19173888;                  // 32,346,624 B
  u16* h2b = (u16*)(wsb + NEED);                           // 131,072 B
  u16* E2bT = (u16*)(wsb + NEED + 131072);                 // 4,194,304 B
  const size_t NEED2 = NEED + 131072 + 4194304;            // 36,672,000 B

  int mf = (ws_size >= NEED2) ? 1 : 0;

  k_hidden<<<512, 128, 0, stream>>>(emb, W1, b1, E1, e1, h1_tab, h2_tab, h2b, mf);
  k_transpose<<<8192, 256, 0, stream>>>(E2, E2p, E2bT, mf);
  k_trans<<<512, 256, 0, stream>>>(h1_tab, W2, b2, ltrans);
  if (mf) {
    k_emit_lse<<<dim3(32, 16), 256, 0, stream>>>(h2b, E2bT, e2, lse_tab);
  } else {
    k_emit_gemm<<<dim3(256, 8), 256, 0, stream>>>(h2_tab, E2, e2, part_m, part_s);
    k_lsecomb<<<64, 256, 0, stream>>>(part_m, part_s, lse_tab);
  }
  k_es<<<8192, 64, 0, stream>>>(seq, h2_tab, E2p, e2, lse_tab, es);

  if (ws_size >= NEED) {
    k_mat<<<8192, 64, 0, stream>>>(seq, lengths, ltrans, es, Mb, msc);
    k_prod<<<1024, 64, 0, stream>>>(Mb, msc, C1, s1);
    k_prod<<<128, 64, 0, stream>>>(C1, s1, C2, s2);
    k_final<<<16, 64, 0, stream>>>(C2, s2, es, init_logits, out);
  } else {
    k_forward<<<16, 64, 0, stream>>>(seq, lengths, ltrans, es, init_logits, out);
  }
}

// Round 5
// 96.083 us; speedup vs baseline: 4.2535x; 1.1777x over previous
//
#include <hip/hip_runtime.h>
#include <hip/hip_bf16.h>

// Problem constants
#define BB 16
#define TT 512
#define KK 32
#define VV 512
#define DD 64
#define HH 128
#define KV (KK*VV)   // 16384
#define KKK (KK*KK)  // 1024

#define INV_LN2 1.4426950408889634f
#define LN2 0.6931471805599453f

typedef unsigned short u16;
typedef __attribute__((ext_vector_type(8))) short short8;
typedef __attribute__((ext_vector_type(8))) unsigned short ushort8;
typedef __attribute__((ext_vector_type(16))) float f32x16;
typedef __attribute__((ext_vector_type(4))) unsigned int uint4v;

__device__ __forceinline__ float fexp2(float x) { return __builtin_amdgcn_exp2f(x); }
__device__ __forceinline__ float flog2(float x) { return __builtin_amdgcn_logf(x); }

// float -> bf16 bits, round-nearest-even (finite inputs only)
__device__ __forceinline__ u16 f2bf(float f) {
  unsigned u = __builtin_bit_cast(unsigned, f);
  u += 0x7FFFu + ((u >> 16) & 1u);
  return (u16)(u >> 16);
}
__device__ __forceinline__ float bf2f(u16 v) {
  return __builtin_bit_cast(float, ((unsigned)v) << 16);
}

// 128-dim half-dot of two bf16 rows (64 elements each, this lane's half)
__device__ __forceinline__ float es_dot(const u16* __restrict__ erow,
                                        const u16* __restrict__ hrow) {
  float dot = 0.f;
#pragma unroll
  for (int r = 0; r < 8; ++r) {
    short8 ev = ((const short8*)erow)[r];
    short8 hv = ((const short8*)hrow)[r];
#pragma unroll
    for (int e = 0; e < 8; ++e)
      dot += bf2f((u16)ev[e]) * bf2f((u16)hv[e]);
  }
  return dot;
}

// One step of the 32x32 matrix-chain product: D = A(fr0,fr1) x D.
// D layout: lane(l) col=l&31, rows (r&3)+8*(r>>2)+4*(l>>5).
__device__ __forceinline__ void mul_step(short8 fr0, short8 fr1, int h,
                                         float* D) {
  float e0[8], e1[8];
#pragma unroll
  for (int i2 = 0; i2 < 4; ++i2) {
    float x0 = __shfl_xor(D[i2], 32);
    float y0 = __shfl_xor(D[4 + i2], 32);
    e0[i2] = (h == 0) ? D[i2] : y0;
    e0[4 + i2] = (h == 0) ? x0 : D[4 + i2];
    float x1 = __shfl_xor(D[8 + i2], 32);
    float y1 = __shfl_xor(D[12 + i2], 32);
    e1[i2] = (h == 0) ? D[8 + i2] : y1;
    e1[4 + i2] = (h == 0) ? x1 : D[12 + i2];
  }
  short8 B0, B1;
#pragma unroll
  for (int e = 0; e < 8; ++e) {
    B0[e] = (short)f2bf(e0[e]);
    B1[e] = (short)f2bf(e1[e]);
  }
  f32x16 dn = {};
  dn = __builtin_amdgcn_mfma_f32_32x32x16_bf16(fr0, B0, dn, 0, 0, 0);
  dn = __builtin_amdgcn_mfma_f32_32x32x16_bf16(fr1, B1, dn, 0, 0, 0);
#pragma unroll
  for (int r = 0; r < 16; ++r) D[r] = dn[r];
}

__device__ __forceinline__ void ident_D(int j, int h, float* D) {
#pragma unroll
  for (int r = 0; r < 16; ++r) D[r] = 0.f;
  if (((j >> 2) & 1) == h) D[(j & 3) | ((j >> 3) << 2)] = 1.0f;
}

// ---------------------------------------------------------------------------
// K0: LDS-tiled transpose E2 (128 x 16384 f32) -> E2bT (16384 x 128 bf16)
// grid (256, 4), block 256. Tile: 32 h x 64 col.
__global__ __launch_bounds__(256) void k_transpose(
    const float* __restrict__ E2, u16* __restrict__ E2bT) {
  __shared__ float tl[32][65];
  int c0 = blockIdx.x * 64, h0 = blockIdx.y * 32;
  int tid = threadIdx.x;
  int r = tid >> 6, c = tid & 63;
#pragma unroll
  for (int rr = 0; rr < 8; ++rr)
    tl[r * 8 + rr][c] = E2[(size_t)(h0 + r * 8 + rr) * KV + c0 + c];
  __syncthreads();
  int cw = tid >> 3, hb = tid & 7;
#pragma unroll
  for (int pass = 0; pass < 2; ++pass) {
    int cc = pass * 32 + cw;
    unsigned lo = (unsigned)f2bf(tl[hb * 4 + 0][cc]) |
                  ((unsigned)f2bf(tl[hb * 4 + 1][cc]) << 16);
    unsigned hi = (unsigned)f2bf(tl[hb * 4 + 2][cc]) |
                  ((unsigned)f2bf(tl[hb * 4 + 3][cc]) << 16);
    uint2 v;
    v.x = lo;
    v.y = hi;
    *(uint2*)(E2bT + (size_t)(c0 + cc) * HH + h0 + hb * 4) = v;
  }
}

// ---------------------------------------------------------------------------
// K1: fused hidden + transition tables. grid 128 blocks x 256, 4 tokens/block.
// Writes h2b (bf16) and ltrans (transposed, log2-domain, row-log-softmaxed).
__global__ __launch_bounds__(256) void k_front(
    const float* __restrict__ emb, const float* __restrict__ W1,
    const float* __restrict__ b1, const float* __restrict__ E1,
    const float* __restrict__ e1, const float* __restrict__ W2,
    const float* __restrict__ b2, float* __restrict__ ltrans,
    u16* __restrict__ h2b) {
  __shared__ float embs[4][64];
  __shared__ float h1s[4][128];
  __shared__ float lg[4][32 * 33];
  __shared__ float lsev[4][32];
  int u0 = blockIdx.x * 4, tid = threadIdx.x;
  {
    int tok = tid >> 6, d = tid & 63;
    embs[tok][d] = emb[(u0 + tok) * DD + d];
  }
  __syncthreads();
#pragma unroll
  for (int p = 0; p < 2; ++p) {
    int tok = p * 2 + (tid >> 7), hh = tid & 127;
    float a1 = b1[hh], a2 = e1[hh];
#pragma unroll 8
    for (int d = 0; d < DD; ++d) {
      float xv = embs[tok][d];
      a1 += xv * W1[d * HH + hh];
      a2 += xv * E1[d * HH + hh];
    }
    h1s[tok][hh] = fmaxf(a1, 0.f);
    h2b[(u0 + tok) * HH + hh] = f2bf(fmaxf(a2, 0.f));
  }
  __syncthreads();
  float acc[4][4];
#pragma unroll
  for (int r = 0; r < 4; ++r) {
    float bb = b2[tid + r * 256];
#pragma unroll
    for (int tok = 0; tok < 4; ++tok) acc[tok][r] = bb;
  }
#pragma unroll 2
  for (int hh = 0; hh < HH; ++hh) {
    float w0 = W2[hh * KKK + tid];
    float w1 = W2[hh * KKK + tid + 256];
    float w2v = W2[hh * KKK + tid + 512];
    float w3 = W2[hh * KKK + tid + 768];
#pragma unroll
    for (int tok = 0; tok < 4; ++tok) {
      float hv = h1s[tok][hh];
      acc[tok][0] += hv * w0;
      acc[tok][1] += hv * w1;
      acc[tok][2] += hv * w2v;
      acc[tok][3] += hv * w3;
    }
  }
#pragma unroll
  for (int tok = 0; tok < 4; ++tok)
#pragma unroll
    for (int r = 0; r < 4; ++r) {
      int cc = tid + r * 256;  // cc = i*32 + j
      lg[tok][(cc >> 5) * 33 + (cc & 31)] = acc[tok][r] * INV_LN2;
    }
  __syncthreads();
  if (tid < 128) {
    int tok = tid >> 5, i = tid & 31;
    float m = -1e30f;
    for (int jj = 0; jj < KK; ++jj) m = fmaxf(m, lg[tok][i * 33 + jj]);
    float s = 0.f;
    for (int jj = 0; jj < KK; ++jj) s += fexp2(lg[tok][i * 33 + jj] - m);
    lsev[tok][i] = m + flog2(s);
  }
  __syncthreads();
#pragma unroll
  for (int tok = 0; tok < 4; ++tok)
#pragma unroll
    for (int r = 0; r < 4; ++r) {
      int cc = tid + r * 256;  // cc = j*32 + i (transposed layout)
      int jj = cc >> 5, ii = cc & 31;
      ltrans[(u0 + tok) * KKK + jj * KK + ii] =
          lg[tok][ii * 33 + jj] - lsev[tok][ii];
    }
}

// ---------------------------------------------------------------------------
// K2: emission GEMM via MFMA + fused LSE over V. Output lse2 (log2 domain).
// grid: (32 k-groups, 16 row-tiles), block 256 (4 waves).
__global__ __launch_bounds__(256) void k_emit_lse(
    const u16* __restrict__ h2b, const u16* __restrict__ E2bT,
    const float* __restrict__ e2, float* __restrict__ lse2_tab) {
  int k = blockIdx.x;        // 0..31
  int u0 = blockIdx.y * 32;  // row tile base
  int tid = threadIdx.x;
  int w = tid >> 6, l = tid & 63;
  int h = l >> 5, j = l & 31;
  __shared__ float lm[4 * 32], ls[4 * 32];

  short8 A[8];
#pragma unroll
  for (int kh = 0; kh < 8; ++kh)
    A[kh] = *(const short8*)(h2b + (u0 + j) * HH + kh * 16 + h * 8);

  float m[16], s[16];
#pragma unroll
  for (int r = 0; r < 16; ++r) { m[r] = -1e30f; s[r] = 0.f; }

#pragma unroll
  for (int c = 0; c < 4; ++c) {
    int ct = w * 4 + c;
    int col = k * 512 + ct * 32 + j;
    const u16* bp = E2bT + (size_t)col * HH + h * 8;
    f32x16 acc = {};
#pragma unroll
    for (int kh = 0; kh < 8; ++kh) {
      short8 Bf = *(const short8*)(bp + kh * 16);
      acc = __builtin_amdgcn_mfma_f32_32x32x16_bf16(A[kh], Bf, acc, 0, 0, 0);
    }
    float e2v = e2[col] * INV_LN2;
#pragma unroll
    for (int r = 0; r < 16; ++r) {
      float v2 = acc[r] * INV_LN2 + e2v;
      float mn = fmaxf(m[r], v2);
      s[r] = s[r] * fexp2(m[r] - mn) + fexp2(v2 - mn);
      m[r] = mn;
    }
  }
#pragma unroll
  for (int r = 0; r < 16; ++r) {
#pragma unroll
    for (int d = 1; d < 32; d <<= 1) {
      float mo = __shfl_xor(m[r], d);
      float so = __shfl_xor(s[r], d);
      float mn = fmaxf(m[r], mo);
      s[r] = s[r] * fexp2(m[r] - mn) + so * fexp2(mo - mn);
      m[r] = mn;
    }
  }
  if (j == 0) {
#pragma unroll
    for (int r = 0; r < 16; ++r) {
      int row = (r & 3) + 8 * (r >> 2) + 4 * h;
      lm[w * 32 + row] = m[r];
      ls[w * 32 + row] = s[r];
    }
  }
  __syncthreads();
  if (tid < 32) {
    float mm = lm[tid], ss = ls[tid];
#pragma unroll
    for (int w2 = 1; w2 < 4; ++w2) {
      float mo = lm[w2 * 32 + tid], so = ls[w2 * 32 + tid];
      float mn = fmaxf(mm, mo);
      ss = ss * fexp2(mm - mn) + so * fexp2(mo - mn);
      mm = mn;
    }
    lse2_tab[(u0 + tid) * KK + k] = mm + flog2(ss);
  }
}

// ---------------------------------------------------------------------------
// K3: fused es + step-matrix build + chunk-of-8 product.
// grid 256 x 256 (4 waves/block); wave handles chunk c = bid*4+w of 1024.
// Writes C1 (normalized bf16 32x32 row-major) + s1 (accumulated log2 scale).
__global__ __launch_bounds__(256) void k_matprod(
    const int* __restrict__ seq, const int* __restrict__ lengths,
    const float* __restrict__ ltrans, const u16* __restrict__ h2b,
    const u16* __restrict__ E2bT, const float* __restrict__ e2,
    const float* __restrict__ lse2, u16* __restrict__ C1,
    float* __restrict__ s1) {
  __shared__ float tmp[4][32 * 33];
  int w = threadIdx.x >> 6, l = threadIdx.x & 63;
  int c = blockIdx.x * 4 + w;
  int b = c >> 6, t0 = (c & 63) * 8;
  int j = l & 31, h = l >> 5;
  int len = lengths[b];
  len = (len < 1) ? 1 : ((len > TT) ? TT : len);
  const int* sb = seq + b * TT;

  float D[16];
  ident_D(j, h, D);
  float sacc = 0.f;

  for (int s = 0; s < 8; ++s) {
    int t = t0 + s;
    if (t == 0 || t >= len) continue;  // identity slot: skip
    int u = sb[t - 1], y = sb[t];
    // es_j = (dot(h2[u], E2col(j,y)) + e2)/ln2 - lse2[u,j]
    float dot = es_dot(E2bT + (size_t)(j * VV + y) * HH + h * 64,
                       h2b + u * HH + h * 64);
    dot += __shfl_xor(dot, 32);
    float esj = (dot + e2[j * VV + y]) * INV_LN2 - lse2[u * KK + j];
    const float4* p4 = (const float4*)(ltrans + u * KKK + j * KK + h * 16);
    float4 q0 = p4[0], q1 = p4[1], q2 = p4[2], q3 = p4[3];
    float lgv[16] = {q0.x, q0.y, q0.z, q0.w, q1.x, q1.y, q1.z, q1.w,
                     q2.x, q2.y, q2.z, q2.w, q3.x, q3.y, q3.z, q3.w};
#pragma unroll
    for (int e = 0; e < 16; ++e) lgv[e] += esj;
    float m = lgv[0];
#pragma unroll
    for (int e = 1; e < 16; ++e) m = fmaxf(m, lgv[e]);
#pragma unroll
    for (int d = 1; d < 64; d <<= 1) m = fmaxf(m, __shfl_xor(m, d));
    sacc += m;
    // normalized bf16 elements, packed in u32 pairs
    unsigned pk[8];
#pragma unroll
    for (int p = 0; p < 8; ++p)
      pk[p] = (unsigned)f2bf(fexp2(lgv[2 * p] - m)) |
              ((unsigned)f2bf(fexp2(lgv[2 * p + 1] - m)) << 16);
    // exchange with partner lane (l^32) to build A-fragments
    unsigned rcv[4];
#pragma unroll
    for (int p = 0; p < 4; ++p)
      rcv[p] = (unsigned)__shfl_xor((int)(h == 0 ? pk[4 + p] : pk[p]), 32);
    unsigned f0[4], f1[4];
#pragma unroll
    for (int p = 0; p < 4; ++p) {
      f0[p] = h == 0 ? pk[p] : rcv[p];
      f1[p] = h == 0 ? rcv[p] : pk[4 + p];
    }
    short8 fr0 = __builtin_bit_cast(short8, (uint4v){f0[0], f0[1], f0[2], f0[3]});
    short8 fr1 = __builtin_bit_cast(short8, (uint4v){f1[0], f1[1], f1[2], f1[3]});
    mul_step(fr0, fr1, h, D);
  }

  // normalize D and emit row-major bf16 + scale
  float mx = D[0];
#pragma unroll
  for (int r = 1; r < 16; ++r) mx = fmaxf(mx, D[r]);
#pragma unroll
  for (int d = 1; d < 64; d <<= 1) mx = fmaxf(mx, __shfl_xor(mx, d));
  float inv = 1.0f / mx;
#pragma unroll
  for (int r = 0; r < 16; ++r) {
    int row = (r & 3) + 8 * (r >> 2) + 4 * h;
    tmp[w][row * 33 + j] = D[r] * inv;
  }
  ushort8 w0, w1;
#pragma unroll
  for (int e = 0; e < 8; ++e) {
    w0[e] = f2bf(tmp[w][j * 33 + h * 16 + e]);
    w1[e] = f2bf(tmp[w][j * 33 + h * 16 + 8 + e]);
  }
  u16* op = C1 + (size_t)c * 1024 + j * 32 + h * 16;
  *(ushort8*)op = w0;
  *(ushort8*)(op + 8) = w1;
  if (l == 0) s1[c] = flog2(mx) + sacc;
}

// ---------------------------------------------------------------------------
// K4: final reduce. 16 blocks x 512 (8 waves). Wave w: product of 8 C1 chunks
// -> LDS. Wave 0: product of the 8 LDS mats + alpha0/es(t=0) + NLL.
__global__ __launch_bounds__(512) void k_final2(
    const u16* __restrict__ C1, const float* __restrict__ s1,
    const int* __restrict__ seq, const u16* __restrict__ h2b,
    const u16* __restrict__ E2bT, const float* __restrict__ e2,
    const float* __restrict__ lse2, const float* __restrict__ init_logits,
    float* __restrict__ out) {
  __shared__ u16 mats[8][1024];
  __shared__ float scs[8];
  int b = blockIdx.x;
  int w = threadIdx.x >> 6, l = threadIdx.x & 63;
  int j = l & 31, h = l >> 5;

  float D[16];
  ident_D(j, h, D);
  const u16* base = C1 + ((size_t)b * 64 + w * 8) * 1024;
#pragma unroll
  for (int s = 0; s < 8; ++s) {
    short8 fr0 = *(const short8*)(base + s * 1024 + j * 32 + h * 8);
    short8 fr1 = *(const short8*)(base + s * 1024 + j * 32 + h * 8 + 16);
    mul_step(fr0, fr1, h, D);
  }
  float mx = D[0];
#pragma unroll
  for (int r = 1; r < 16; ++r) mx = fmaxf(mx, D[r]);
#pragma unroll
  for (int d = 1; d < 64; d <<= 1) mx = fmaxf(mx, __shfl_xor(mx, d));
  float inv = 1.0f / mx;
#pragma unroll
  for (int r = 0; r < 16; ++r) {
    int row = (r & 3) + 8 * (r >> 2) + 4 * h;
    mats[w][row * 32 + j] = f2bf(D[r] * inv);
  }
  float si = (l < 8) ? s1[b * 64 + w * 8 + l] : 0.f;
#pragma unroll
  for (int d = 1; d < 64; d <<= 1) si += __shfl_xor(si, d);
  if (l == 0) scs[w] = flog2(mx) + si;
  __syncthreads();

  if (w == 0) {
    float D2[16];
    ident_D(j, h, D2);
#pragma unroll
    for (int s = 0; s < 8; ++s) {
      short8 fr0 = *(const short8*)(&mats[s][j * 32 + h * 8]);
      short8 fr1 = *(const short8*)(&mats[s][j * 32 + h * 8 + 16]);
      mul_step(fr0, fr1, h, D2);
    }
    // es(b, 0, j): input token at t=0 is the start token 0
    int y0 = seq[b * TT];
    float dot = es_dot(E2bT + (size_t)(j * VV + y0) * HH + h * 64,
                       h2b + h * 64);
    dot += __shfl_xor(dot, 32);
    float esj = (dot + e2[j * VV + y0]) * INV_LN2 - lse2[j];
    // alpha0 (log2 domain)
    float il = init_logits[j] * INV_LN2;
    float m0 = il;
#pragma unroll
    for (int d = 1; d < 32; d <<= 1) m0 = fmaxf(m0, __shfl_xor(m0, d));
    float s0 = fexp2(il - m0);
#pragma unroll
    for (int d = 1; d < 32; d <<= 1) s0 += __shfl_xor(s0, d);
    float lse0 = m0 + flog2(s0);
    float z = il - lse0 + esj;
    float am = z;
#pragma unroll
    for (int d = 1; d < 32; d <<= 1) am = fmaxf(am, __shfl_xor(am, d));
    float a0 = fexp2(z - am);
    float colsum = 0.f;
#pragma unroll
    for (int r = 0; r < 16; ++r) colsum += D2[r];
    float p = a0 * colsum;
#pragma unroll
    for (int d = 1; d < 64; d <<= 1) p += __shfl_xor(p, d);
    float sct = (l < 8) ? scs[l] : 0.f;
#pragma unroll
    for (int d = 1; d < 64; d <<= 1) sct += __shfl_xor(sct, d);
    if (l == 0) out[b] = -LN2 * (flog2(p) + am + sct);
  }
}

// ---------------------------------------------------------------------------
extern "C" void kernel_launch(void* const* d_in, const int* in_sizes, int n_in,
                              void* d_out, int out_size, void* d_ws,
                              size_t ws_size, hipStream_t stream) {
  const int* seq = (const int*)d_in[0];
  const int* lengths = (const int*)d_in[1];
  const float* emb = (const float*)d_in[2];
  const float* W1 = (const float*)d_in[3];
  const float* b1 = (const float*)d_in[4];
  const float* W2 = (const float*)d_in[5];
  const float* b2 = (const float*)d_in[6];
  const float* E1 = (const float*)d_in[7];
  const float* e1 = (const float*)d_in[8];
  const float* E2 = (const float*)d_in[9];
  const float* e2 = (const float*)d_in[10];
  const float* init_logits = (const float*)d_in[11];
  float* out = (float*)d_out;

  char* wsb = (char*)d_ws;
  float* ltrans = (float*)(wsb + 0);            // 2,097,152 B
  u16* h2b = (u16*)(wsb + 2097152);             //   131,072 B
  u16* E2bT = (u16*)(wsb + 2228224);            // 4,194,304 B
  float* lse2 = (float*)(wsb + 6422528);        //    65,536 B
  u16* C1 = (u16*)(wsb + 6488064);              // 2,097,152 B
  float* s1 = (float*)(wsb + 8585216);          //     4,096 B

  k_transpose<<<dim3(256, 4), 256, 0, stream>>>(E2, E2bT);
  k_front<<<128, 256, 0, stream>>>(emb, W1, b1, E1, e1, W2, b2, ltrans, h2b);
  k_emit_lse<<<dim3(32, 16), 256, 0, stream>>>(h2b, E2bT, e2, lse2);
  k_matprod<<<256, 256, 0, stream>>>(seq, lengths, ltrans, h2b, E2bT, e2,
                                     lse2, C1, s1);
  k_final2<<<16, 512, 0, stream>>>(C1, s1, seq, h2b, E2bT, e2, lse2,
                                   init_logits, out);
}

// Round 6
// 88.560 us; speedup vs baseline: 4.6149x; 1.0849x over previous
//
#include <hip/hip_runtime.h>
#include <hip/hip_bf16.h>

// Problem constants
#define BB 16
#define TT 512
#define KK 32
#define VV 512
#define DD 64
#define HH 128
#define KV (KK*VV)   // 16384
#define KKK (KK*KK)  // 1024

#define INV_LN2 1.4426950408889634f
#define LN2 0.6931471805599453f

typedef unsigned short u16;
typedef __attribute__((ext_vector_type(8))) short short8;
typedef __attribute__((ext_vector_type(8))) unsigned short ushort8;
typedef __attribute__((ext_vector_type(16))) float f32x16;
typedef __attribute__((ext_vector_type(4))) unsigned int uint4v;

__device__ __forceinline__ float fexp2(float x) { return __builtin_amdgcn_exp2f(x); }
__device__ __forceinline__ float flog2(float x) { return __builtin_amdgcn_logf(x); }

// float -> bf16 bits, round-nearest-even (finite inputs only)
__device__ __forceinline__ u16 f2bf(float f) {
  unsigned u = __builtin_bit_cast(unsigned, f);
  u += 0x7FFFu + ((u >> 16) & 1u);
  return (u16)(u >> 16);
}
__device__ __forceinline__ float bf2f(u16 v) {
  return __builtin_bit_cast(float, ((unsigned)v) << 16);
}

// 128-dim half-dot of two bf16 rows (64 elements each, this lane's half)
__device__ __forceinline__ float es_dot(const u16* __restrict__ erow,
                                        const u16* __restrict__ hrow) {
  float dot = 0.f;
#pragma unroll
  for (int r = 0; r < 8; ++r) {
    short8 ev = ((const short8*)erow)[r];
    short8 hv = ((const short8*)hrow)[r];
#pragma unroll
    for (int e = 0; e < 8; ++e)
      dot += bf2f((u16)ev[e]) * bf2f((u16)hv[e]);
  }
  return dot;
}

// One step of the 32x32 matrix-chain product: D = A(fr0,fr1) x D.
// D layout: lane(l) col=l&31, rows (r&3)+8*(r>>2)+4*(l>>5).
__device__ __forceinline__ void mul_step(short8 fr0, short8 fr1, int h,
                                         float* D) {
  float e0[8], e1[8];
#pragma unroll
  for (int i2 = 0; i2 < 4; ++i2) {
    float x0 = __shfl_xor(D[i2], 32);
    float y0 = __shfl_xor(D[4 + i2], 32);
    e0[i2] = (h == 0) ? D[i2] : y0;
    e0[4 + i2] = (h == 0) ? x0 : D[4 + i2];
    float x1 = __shfl_xor(D[8 + i2], 32);
    float y1 = __shfl_xor(D[12 + i2], 32);
    e1[i2] = (h == 0) ? D[8 + i2] : y1;
    e1[4 + i2] = (h == 0) ? x1 : D[12 + i2];
  }
  short8 B0, B1;
#pragma unroll
  for (int e = 0; e < 8; ++e) {
    B0[e] = (short)f2bf(e0[e]);
    B1[e] = (short)f2bf(e1[e]);
  }
  f32x16 dn = {};
  dn = __builtin_amdgcn_mfma_f32_32x32x16_bf16(fr0, B0, dn, 0, 0, 0);
  dn = __builtin_amdgcn_mfma_f32_32x32x16_bf16(fr1, B1, dn, 0, 0, 0);
#pragma unroll
  for (int r = 0; r < 16; ++r) D[r] = dn[r];
}

__device__ __forceinline__ void ident_D(int j, int h, float* D) {
#pragma unroll
  for (int r = 0; r < 16; ++r) D[r] = 0.f;
  if (((j >> 2) & 1) == h) D[(j & 3) | ((j >> 3) << 2)] = 1.0f;
}

// ---------------------------------------------------------------------------
// K0: merged prep. Blocks [0,1024): LDS-tiled transpose E2 -> E2bT (bf16).
// Blocks [1024,1152): fused hidden + transition tables (4 tokens/block).
__global__ __launch_bounds__(256) void k_prep(
    const float* __restrict__ E2, u16* __restrict__ E2bT,
    const float* __restrict__ emb, const float* __restrict__ W1,
    const float* __restrict__ b1, const float* __restrict__ E1,
    const float* __restrict__ e1, const float* __restrict__ W2,
    const float* __restrict__ b2, float* __restrict__ ltrans,
    u16* __restrict__ h2b) {
  __shared__ float tl[32][65];
  __shared__ float embs[4][64];
  __shared__ float h1s[4][128];
  __shared__ float lg[4][32 * 33];
  __shared__ float lsev[4][32];
  int tid = threadIdx.x;

  if (blockIdx.x < 1024) {
    // ---- transpose tile: 32 h x 64 col ----
    int c0 = (blockIdx.x & 255) * 64, h0 = (blockIdx.x >> 8) * 32;
    int r = tid >> 6, c = tid & 63;
#pragma unroll
    for (int rr = 0; rr < 8; ++rr)
      tl[r * 8 + rr][c] = E2[(size_t)(h0 + r * 8 + rr) * KV + c0 + c];
    __syncthreads();
    int cw = tid >> 3, hb = tid & 7;
#pragma unroll
    for (int pass = 0; pass < 2; ++pass) {
      int cc = pass * 32 + cw;
      unsigned lo = (unsigned)f2bf(tl[hb * 4 + 0][cc]) |
                    ((unsigned)f2bf(tl[hb * 4 + 1][cc]) << 16);
      unsigned hi = (unsigned)f2bf(tl[hb * 4 + 2][cc]) |
                    ((unsigned)f2bf(tl[hb * 4 + 3][cc]) << 16);
      uint2 v;
      v.x = lo;
      v.y = hi;
      *(uint2*)(E2bT + (size_t)(c0 + cc) * HH + h0 + hb * 4) = v;
    }
    return;
  }

  // ---- front: hidden + transition ----
  int u0 = (blockIdx.x - 1024) * 4;
  {
    int tok = tid >> 6, d = tid & 63;
    embs[tok][d] = emb[(u0 + tok) * DD + d];
  }
  __syncthreads();
#pragma unroll
  for (int p = 0; p < 2; ++p) {
    int tok = p * 2 + (tid >> 7), hh = tid & 127;
    float a1 = b1[hh], a2 = e1[hh];
#pragma unroll 8
    for (int d = 0; d < DD; ++d) {
      float xv = embs[tok][d];
      a1 += xv * W1[d * HH + hh];
      a2 += xv * E1[d * HH + hh];
    }
    h1s[tok][hh] = fmaxf(a1, 0.f);
    h2b[(u0 + tok) * HH + hh] = f2bf(fmaxf(a2, 0.f));
  }
  __syncthreads();
  float acc[4][4];
#pragma unroll
  for (int r = 0; r < 4; ++r) {
    float bb = b2[tid + r * 256];
#pragma unroll
    for (int tok = 0; tok < 4; ++tok) acc[tok][r] = bb;
  }
#pragma unroll 2
  for (int hh = 0; hh < HH; ++hh) {
    float w0 = W2[hh * KKK + tid];
    float w1 = W2[hh * KKK + tid + 256];
    float w2v = W2[hh * KKK + tid + 512];
    float w3 = W2[hh * KKK + tid + 768];
#pragma unroll
    for (int tok = 0; tok < 4; ++tok) {
      float hv = h1s[tok][hh];
      acc[tok][0] += hv * w0;
      acc[tok][1] += hv * w1;
      acc[tok][2] += hv * w2v;
      acc[tok][3] += hv * w3;
    }
  }
#pragma unroll
  for (int tok = 0; tok < 4; ++tok)
#pragma unroll
    for (int r = 0; r < 4; ++r) {
      int cc = tid + r * 256;  // cc = i*32 + j
      lg[tok][(cc >> 5) * 33 + (cc & 31)] = acc[tok][r] * INV_LN2;
    }
  __syncthreads();
  if (tid < 128) {
    int tok = tid >> 5, i = tid & 31;
    float m = -1e30f;
    for (int jj = 0; jj < KK; ++jj) m = fmaxf(m, lg[tok][i * 33 + jj]);
    float s = 0.f;
    for (int jj = 0; jj < KK; ++jj) s += fexp2(lg[tok][i * 33 + jj] - m);
    lsev[tok][i] = m + flog2(s);
  }
  __syncthreads();
#pragma unroll
  for (int tok = 0; tok < 4; ++tok)
#pragma unroll
    for (int r = 0; r < 4; ++r) {
      int cc = tid + r * 256;  // cc = j*32 + i (transposed layout)
      int jj = cc >> 5, ii = cc & 31;
      ltrans[(u0 + tok) * KKK + jj * KK + ii] =
          lg[tok][ii * 33 + jj] - lsev[tok][ii];
    }
}

// ---------------------------------------------------------------------------
// K2: emission GEMM via MFMA + fused LSE over V (no-max: logits are tiny,
// direct sum of exp2 in f32 is exact to well past the needed precision).
// grid: (32 k-groups, 16 row-tiles), block 256 (4 waves).
__global__ __launch_bounds__(256) void k_emit_lse(
    const u16* __restrict__ h2b, const u16* __restrict__ E2bT,
    const float* __restrict__ e2, float* __restrict__ lse2_tab) {
  int k = blockIdx.x;        // 0..31
  int u0 = blockIdx.y * 32;  // row tile base
  int tid = threadIdx.x;
  int w = tid >> 6, l = tid & 63;
  int h = l >> 5, j = l & 31;
  __shared__ float ls[4 * 32];

  short8 A[8];
#pragma unroll
  for (int kh = 0; kh < 8; ++kh)
    A[kh] = *(const short8*)(h2b + (u0 + j) * HH + kh * 16 + h * 8);

  float s[16];
#pragma unroll
  for (int r = 0; r < 16; ++r) s[r] = 0.f;

#pragma unroll
  for (int c = 0; c < 4; ++c) {
    int ct = w * 4 + c;
    int col = k * 512 + ct * 32 + j;
    const u16* bp = E2bT + (size_t)col * HH + h * 8;
    f32x16 acc = {};
#pragma unroll
    for (int kh = 0; kh < 8; ++kh) {
      short8 Bf = *(const short8*)(bp + kh * 16);
      acc = __builtin_amdgcn_mfma_f32_32x32x16_bf16(A[kh], Bf, acc, 0, 0, 0);
    }
    float e2v = e2[col] * INV_LN2;
#pragma unroll
    for (int r = 0; r < 16; ++r) s[r] += fexp2(acc[r] * INV_LN2 + e2v);
  }
  // sum over the 32 cols held across lanes (within each half)
#pragma unroll
  for (int r = 0; r < 16; ++r) {
#pragma unroll
    for (int d = 1; d < 32; d <<= 1) s[r] += __shfl_xor(s[r], d);
  }
  if (j == 0) {
#pragma unroll
    for (int r = 0; r < 16; ++r) {
      int row = (r & 3) + 8 * (r >> 2) + 4 * h;
      ls[w * 32 + row] = s[r];
    }
  }
  __syncthreads();
  if (tid < 32) {
    float total = ls[tid] + ls[32 + tid] + ls[64 + tid] + ls[96 + tid];
    lse2_tab[(u0 + tid) * KK + k] = flog2(total);
  }
}

// ---------------------------------------------------------------------------
// K3: fused es + step-matrix build + chunk-of-8 product, phase-split:
// Phase A builds all 8 fragment pairs (independent load chains -> full MLP),
// Phase B chains the 8 MFMA multiplies. Scale = per-step max over esj only.
// grid 256 x 256 (4 waves/block); wave handles chunk c = bid*4+w of 1024.
__global__ __launch_bounds__(256) void k_matprod(
    const int* __restrict__ seq, const int* __restrict__ lengths,
    const float* __restrict__ ltrans, const u16* __restrict__ h2b,
    const u16* __restrict__ E2bT, const float* __restrict__ e2,
    const float* __restrict__ lse2, u16* __restrict__ C1,
    float* __restrict__ s1) {
  __shared__ float tmp[4][32 * 33];
  int w = threadIdx.x >> 6, l = threadIdx.x & 63;
  int c = blockIdx.x * 4 + w;
  int b = c >> 6, t0 = (c & 63) * 8;
  int j = l & 31, h = l >> 5;
  int len = lengths[b];
  len = (len < 1) ? 1 : ((len > TT) ? TT : len);
  const int* sb = seq + b * TT;
  int tlo = (t0 < 1) ? 1 : t0;
  int thi = (t0 + 8 < len) ? (t0 + 8) : len;

  u16* op = C1 + (size_t)c * 1024 + j * 32 + h * 16;
  if (tlo >= thi) {  // fully identity chunk (wave-uniform)
    ushort8 w0v, w1v;
#pragma unroll
    for (int e = 0; e < 8; ++e) {
      w0v[e] = ((h * 16 + e) == j) ? (u16)0x3F80 : (u16)0;
      w1v[e] = ((h * 16 + 8 + e) == j) ? (u16)0x3F80 : (u16)0;
    }
    *(ushort8*)op = w0v;
    *(ushort8*)(op + 8) = w1v;
    if (l == 0) s1[c] = 0.f;
    return;
  }

  // ---- Phase A: build 8 fragment pairs ----
  short8 fr0s[8], fr1s[8];
  float sacc = 0.f;
#pragma unroll
  for (int s = 0; s < 8; ++s) {
    int t = t0 + s;
    if (t >= 1 && t < len) {  // wave-uniform
      int u = sb[t - 1], y = sb[t];
      float dot = es_dot(E2bT + (size_t)(j * VV + y) * HH + h * 64,
                         h2b + u * HH + h * 64);
      dot += __shfl_xor(dot, 32);
      float esj = (dot + e2[j * VV + y]) * INV_LN2 - lse2[u * KK + j];
      float m = esj;  // scale = max_j esj (ltrans rows are <= 0)
#pragma unroll
      for (int d = 1; d < 32; d <<= 1) m = fmaxf(m, __shfl_xor(m, d));
      sacc += m;
      const float4* p4 = (const float4*)(ltrans + u * KKK + j * KK + h * 16);
      float4 q0 = p4[0], q1 = p4[1], q2 = p4[2], q3 = p4[3];
      float lgv[16] = {q0.x, q0.y, q0.z, q0.w, q1.x, q1.y, q1.z, q1.w,
                       q2.x, q2.y, q2.z, q2.w, q3.x, q3.y, q3.z, q3.w};
      float off = esj - m;
#pragma unroll
      for (int e = 0; e < 16; ++e) lgv[e] += off;
      unsigned pk[8];
#pragma unroll
      for (int p = 0; p < 8; ++p)
        pk[p] = (unsigned)f2bf(fexp2(lgv[2 * p])) |
                ((unsigned)f2bf(fexp2(lgv[2 * p + 1])) << 16);
      unsigned rcv[4];
#pragma unroll
      for (int p = 0; p < 4; ++p)
        rcv[p] = (unsigned)__shfl_xor((int)(h == 0 ? pk[4 + p] : pk[p]), 32);
      unsigned f0[4], f1[4];
#pragma unroll
      for (int p = 0; p < 4; ++p) {
        f0[p] = h == 0 ? pk[p] : rcv[p];
        f1[p] = h == 0 ? rcv[p] : pk[4 + p];
      }
      fr0s[s] = __builtin_bit_cast(short8, (uint4v){f0[0], f0[1], f0[2], f0[3]});
      fr1s[s] = __builtin_bit_cast(short8, (uint4v){f1[0], f1[1], f1[2], f1[3]});
    } else {
      // identity A-fragment: fr0 covers cols h*8+e, fr1 cols 16+h*8+e
      ushort8 i0, i1;
#pragma unroll
      for (int e = 0; e < 8; ++e) {
        i0[e] = ((h * 8 + e) == j) ? (u16)0x3F80 : (u16)0;
        i1[e] = ((16 + h * 8 + e) == j) ? (u16)0x3F80 : (u16)0;
      }
      fr0s[s] = __builtin_bit_cast(short8, i0);
      fr1s[s] = __builtin_bit_cast(short8, i1);
    }
  }

  // ---- Phase B: chained product ----
  float D[16];
  ident_D(j, h, D);
#pragma unroll
  for (int s = 0; s < 8; ++s) mul_step(fr0s[s], fr1s[s], h, D);

  // normalize D and emit row-major bf16 + scale
  float mx = D[0];
#pragma unroll
  for (int r = 1; r < 16; ++r) mx = fmaxf(mx, D[r]);
#pragma unroll
  for (int d = 1; d < 64; d <<= 1) mx = fmaxf(mx, __shfl_xor(mx, d));
  float inv = 1.0f / mx;
#pragma unroll
  for (int r = 0; r < 16; ++r) {
    int row = (r & 3) + 8 * (r >> 2) + 4 * h;
    tmp[w][row * 33 + j] = D[r] * inv;
  }
  ushort8 w0v, w1v;
#pragma unroll
  for (int e = 0; e < 8; ++e) {
    w0v[e] = f2bf(tmp[w][j * 33 + h * 16 + e]);
    w1v[e] = f2bf(tmp[w][j * 33 + h * 16 + 8 + e]);
  }
  *(ushort8*)op = w0v;
  *(ushort8*)(op + 8) = w1v;
  if (l == 0) s1[c] = flog2(mx) + sacc;
}

// ---------------------------------------------------------------------------
// K4: final reduce. 16 blocks x 512 (8 waves). Wave w: product of 8 C1 chunks
// -> LDS. Wave 0: product of the 8 LDS mats + alpha0/es(t=0) + NLL.
__global__ __launch_bounds__(512) void k_final2(
    const u16* __restrict__ C1, const float* __restrict__ s1,
    const int* __restrict__ seq, const u16* __restrict__ h2b,
    const u16* __restrict__ E2bT, const float* __restrict__ e2,
    const float* __restrict__ lse2, const float* __restrict__ init_logits,
    float* __restrict__ out) {
  __shared__ u16 mats[8][1024];
  __shared__ float scs[8];
  int b = blockIdx.x;
  int w = threadIdx.x >> 6, l = threadIdx.x & 63;
  int j = l & 31, h = l >> 5;

  float D[16];
  ident_D(j, h, D);
  const u16* base = C1 + ((size_t)b * 64 + w * 8) * 1024;
#pragma unroll
  for (int s = 0; s < 8; ++s) {
    short8 fr0 = *(const short8*)(base + s * 1024 + j * 32 + h * 8);
    short8 fr1 = *(const short8*)(base + s * 1024 + j * 32 + h * 8 + 16);
    mul_step(fr0, fr1, h, D);
  }
  float mx = D[0];
#pragma unroll
  for (int r = 1; r < 16; ++r) mx = fmaxf(mx, D[r]);
#pragma unroll
  for (int d = 1; d < 64; d <<= 1) mx = fmaxf(mx, __shfl_xor(mx, d));
  float inv = 1.0f / mx;
#pragma unroll
  for (int r = 0; r < 16; ++r) {
    int row = (r & 3) + 8 * (r >> 2) + 4 * h;
    mats[w][row * 32 + j] = f2bf(D[r] * inv);
  }
  float si = (l < 8) ? s1[b * 64 + w * 8 + l] : 0.f;
#pragma unroll
  for (int d = 1; d < 64; d <<= 1) si += __shfl_xor(si, d);
  if (l == 0) scs[w] = flog2(mx) + si;
  __syncthreads();

  if (w == 0) {
    float D2[16];
    ident_D(j, h, D2);
#pragma unroll
    for (int s = 0; s < 8; ++s) {
      short8 fr0 = *(const short8*)(&mats[s][j * 32 + h * 8]);
      short8 fr1 = *(const short8*)(&mats[s][j * 32 + h * 8 + 16]);
      mul_step(fr0, fr1, h, D2);
    }
    // es(b, 0, j): input token at t=0 is the start token 0
    int y0 = seq[b * TT];
    float dot = es_dot(E2bT + (size_t)(j * VV + y0) * HH + h * 64,
                       h2b + h * 64);
    dot += __shfl_xor(dot, 32);
    float esj = (dot + e2[j * VV + y0]) * INV_LN2 - lse2[j];
    // alpha0 (log2 domain)
    float il = init_logits[j] * INV_LN2;
    float m0 = il;
#pragma unroll
    for (int d = 1; d < 32; d <<= 1) m0 = fmaxf(m0, __shfl_xor(m0, d));
    float s0 = fexp2(il - m0);
#pragma unroll
    for (int d = 1; d < 32; d <<= 1) s0 += __shfl_xor(s0, d);
    float lse0 = m0 + flog2(s0);
    float z = il - lse0 + esj;
    float am = z;
#pragma unroll
    for (int d = 1; d < 32; d <<= 1) am = fmaxf(am, __shfl_xor(am, d));
    float a0 = fexp2(z - am);
    float colsum = 0.f;
#pragma unroll
    for (int r = 0; r < 16; ++r) colsum += D2[r];
    float p = a0 * colsum;
#pragma unroll
    for (int d = 1; d < 64; d <<= 1) p += __shfl_xor(p, d);
    float sct = (l < 8) ? scs[l] : 0.f;
#pragma unroll
    for (int d = 1; d < 64; d <<= 1) sct += __shfl_xor(sct, d);
    if (l == 0) out[b] = -LN2 * (flog2(p) + am + sct);
  }
}

// ---------------------------------------------------------------------------
extern "C" void kernel_launch(void* const* d_in, const int* in_sizes, int n_in,
                              void* d_out, int out_size, void* d_ws,
                              size_t ws_size, hipStream_t stream) {
  const int* seq = (const int*)d_in[0];
  const int* lengths = (const int*)d_in[1];
  const float* emb = (const float*)d_in[2];
  const float* W1 = (const float*)d_in[3];
  const float* b1 = (const float*)d_in[4];
  const float* W2 = (const float*)d_in[5];
  const float* b2 = (const float*)d_in[6];
  const float* E1 = (const float*)d_in[7];
  const float* e1 = (const float*)d_in[8];
  const float* E2 = (const float*)d_in[9];
  const float* e2 = (const float*)d_in[10];
  const float* init_logits = (const float*)d_in[11];
  float* out = (float*)d_out;

  char* wsb = (char*)d_ws;
  float* ltrans = (float*)(wsb + 0);            // 2,097,152 B
  u16* h2b = (u16*)(wsb + 2097152);             //   131,072 B
  u16* E2bT = (u16*)(wsb + 2228224);            // 4,194,304 B
  float* lse2 = (float*)(wsb + 6422528);        //    65,536 B
  u16* C1 = (u16*)(wsb + 6488064);              // 2,097,152 B
  float* s1 = (float*)(wsb + 8585216);          //     4,096 B

  k_prep<<<1152, 256, 0, stream>>>(E2, E2bT, emb, W1, b1, E1, e1, W2, b2,
                                   ltrans, h2b);
  k_emit_lse<<<dim3(32, 16), 256, 0, stream>>>(h2b, E2bT, e2, lse2);
  k_matprod<<<256, 256, 0, stream>>>(seq, lengths, ltrans, h2b, E2bT, e2,
                                     lse2, C1, s1);
  k_final2<<<16, 512, 0, stream>>>(C1, s1, seq, h2b, E2bT, e2, lse2,
                                   init_logits, out);
}